// Round 1
// baseline (1072.485 us; speedup 1.0000x reference)
//
#include <hip/hip_runtime.h>
#include <hip/hip_bf16.h>

#define NN 50000
#define EE 640000
#define HC 128
#define NEG 0.2f
#define BM 64
#define BN 64
#define BK 32

// ---------------- CSR build ----------------

__global__ void k_zero(int* __restrict__ p, int n) {
    int i = blockIdx.x * blockDim.x + threadIdx.x;
    if (i < n) p[i] = 0;
}

__global__ void k_count(const int* __restrict__ ei, int* __restrict__ cnt) {
    int e = blockIdx.x * blockDim.x + threadIdx.x;
    if (e < EE) atomicAdd(&cnt[ei[EE + e]], 1);
}

// single-block exclusive scan of (cnt[i] + 1), offs[NN] = total = EE + NN
__global__ void k_scan(const int* __restrict__ cnt, int* __restrict__ offs) {
    __shared__ int sd[1024];
    __shared__ int carry_s;
    int tid = threadIdx.x;
    if (tid == 0) carry_s = 0;
    __syncthreads();
    for (int base = 0; base < NN; base += 1024) {
        int i = base + tid;
        int v = (i < NN) ? (cnt[i] + 1) : 0;   // +1 = self loop
        sd[tid] = v;
        __syncthreads();
        #pragma unroll
        for (int ofs = 1; ofs < 1024; ofs <<= 1) {
            int t2 = (tid >= ofs) ? sd[tid - ofs] : 0;
            __syncthreads();
            sd[tid] += t2;
            __syncthreads();
        }
        int c = carry_s;
        if (i < NN) offs[i] = c + sd[tid] - v;  // exclusive
        __syncthreads();
        if (tid == 0) carry_s = c + sd[1023];
        __syncthreads();
    }
    if (tid == 0) offs[NN] = carry_s;
}

__global__ void k_selfloop(const int* __restrict__ offs, int* __restrict__ cursor,
                           int* __restrict__ csr) {
    int i = blockIdx.x * blockDim.x + threadIdx.x;
    if (i < NN) { int o = offs[i]; csr[o] = i; cursor[i] = o + 1; }
}

__global__ void k_fill(const int* __restrict__ ei, int* __restrict__ cursor,
                       int* __restrict__ csr) {
    int e = blockIdx.x * blockDim.x + threadIdx.x;
    if (e < EE) {
        int s = ei[e], d = ei[EE + e];
        int pos = atomicAdd(&cursor[d], 1);
        csr[pos] = s;
    }
}

// ---------------- fp32 GEMM: out[N,128] = X[N,K] @ W[K,128] (both Wl and Wr) ----------------
// grid.y in 0..3: y>>1 selects (Wl,xl) vs (Wr,xr); (y&1)*64 is the column base.

__global__ __launch_bounds__(256)
void k_gemm(const float* __restrict__ X, int K,
            const float* __restrict__ Wlp, const float* __restrict__ Wrp,
            float* __restrict__ xl, float* __restrict__ xr) {
    __shared__ float As[BK][BM + 4];   // row stride 68 floats = 272B (16B multiple)
    __shared__ float Bs[BK][BN];

    int by = blockIdx.y;
    const float* W = (by < 2) ? Wlp : Wrp;
    float* out = (by < 2) ? xl : xr;
    int nb = (by & 1) * BN;
    int m0 = blockIdx.x * BM;
    int tid = threadIdx.x;
    int tm = tid & 15, tn = tid >> 4;

    float acc[4][4] = {};

    for (int k0 = 0; k0 < K; k0 += BK) {
        // A tile 64x32, transposed into LDS
        #pragma unroll
        for (int q = 0; q < 2; ++q) {
            int f = tid + q * 256;
            int r = f >> 3;            // row within tile 0..63
            int c4 = (f & 7) * 4;      // k within tile
            int row = m0 + r;
            float4 v = make_float4(0.f, 0.f, 0.f, 0.f);
            if (row < NN) v = *(const float4*)&X[(size_t)row * K + k0 + c4];
            As[c4 + 0][r] = v.x; As[c4 + 1][r] = v.y;
            As[c4 + 2][r] = v.z; As[c4 + 3][r] = v.w;
        }
        // B tile 32x64, natural layout
        #pragma unroll
        for (int q = 0; q < 2; ++q) {
            int f = tid + q * 256;
            int r = f >> 4;            // k 0..31
            int c4 = (f & 15) * 4;     // col 0..60
            *(float4*)&Bs[r][c4] = *(const float4*)&W[(size_t)(k0 + r) * HC + nb + c4];
        }
        __syncthreads();
        #pragma unroll
        for (int kk = 0; kk < BK; ++kk) {
            const float4 a = *(const float4*)&As[kk][tm * 4];
            const float4 bq = *(const float4*)&Bs[kk][tn * 4];
            float av[4] = {a.x, a.y, a.z, a.w};
            float bv[4] = {bq.x, bq.y, bq.z, bq.w};
            #pragma unroll
            for (int i2 = 0; i2 < 4; ++i2)
                #pragma unroll
                for (int j2 = 0; j2 < 4; ++j2)
                    acc[i2][j2] = fmaf(av[i2], bv[j2], acc[i2][j2]);
        }
        __syncthreads();
    }

    #pragma unroll
    for (int i2 = 0; i2 < 4; ++i2) {
        int row = m0 + tm * 4 + i2;
        if (row < NN) {
            #pragma unroll
            for (int j2 = 0; j2 < 4; ++j2)
                out[(size_t)row * HC + nb + tn * 4 + j2] = acc[i2][j2];
        }
    }
}

// ---------------- per-node online-softmax GATv2 aggregation ----------------
// block = node, 128 threads = channels; head h = t>>5 lives in one 32-lane shuffle group.

__global__ __launch_bounds__(128)
void k_edge(const float* __restrict__ xl, const float* __restrict__ xr,
            const float* __restrict__ att, const float* __restrict__ bias,
            const int* __restrict__ offs, const int* __restrict__ csr,
            float* __restrict__ out, int relu) {
    int i = blockIdx.x;
    int t = threadIdx.x;
    float xri = xr[(size_t)i * HC + t];
    float at = att[t];
    int beg = offs[i], end = offs[i + 1];

    float m = -3.0e38f, s = 0.f, acc = 0.f;

    // prefetch first (deg >= 1 guaranteed by self loop)
    int p = beg;
    int jn = csr[p];
    float vn = xl[(size_t)jn * HC + t];

    while (p < end) {
        float v = vn;
        ++p;
        if (p < end) { jn = csr[p]; vn = xl[(size_t)jn * HC + t]; }

        float u = v + xri;
        u = (u > 0.f) ? u : NEG * u;
        u *= at;
        #pragma unroll
        for (int d = 16; d; d >>= 1) u += __shfl_xor(u, d, 32);
        float e = u;                       // per-head logit, broadcast in group

        float mn = fmaxf(m, e);
        float sc = __expf(m - mn);         // first iter: exp(-inf)=0
        float pw = __expf(e - mn);
        s = s * sc + pw;
        acc = acc * sc + pw * v;
        m = mn;
    }

    float o = acc / (s + 1e-16f) + bias[t];
    if (relu) o = fmaxf(o, 0.f);
    out[(size_t)i * HC + t] = o;
}

// ---------------- tail: mean over nodes, classifier ----------------

__global__ void k_colsum(const float* __restrict__ h, float* __restrict__ gsum) {
    int t = threadIdx.x;  // 128
    float s = 0.f;
    for (int i = blockIdx.x; i < NN; i += gridDim.x)
        s += h[(size_t)i * HC + t];
    atomicAdd(&gsum[t], s);
}

__global__ void k_clf(const float* __restrict__ gsum, const float* __restrict__ W,
                      const float* __restrict__ bcls, float* __restrict__ out) {
    int c = threadIdx.x;
    if (c < 2) {
        float s = 0.f;
        const float invn = 1.f / (float)NN;
        for (int k = 0; k < HC; ++k) s += (gsum[k] * invn) * W[k * 2 + c];
        out[c] = s + bcls[c];
    }
}

// ---------------- launch ----------------

extern "C" void kernel_launch(void* const* d_in, const int* in_sizes, int n_in,
                              void* d_out, int out_size, void* d_ws, size_t ws_size,
                              hipStream_t stream) {
    const float* x = (const float*)d_in[0];
    const int* ei = (const int*)d_in[1];
    const float *Wl[4], *Wr[4], *att[4], *bia[4];
    for (int l = 0; l < 4; ++l) {
        Wl[l] = (const float*)d_in[2 + 4 * l];
        Wr[l] = (const float*)d_in[3 + 4 * l];
        att[l] = (const float*)d_in[4 + 4 * l];
        bia[l] = (const float*)d_in[5 + 4 * l];
    }
    const float* clfW = (const float*)d_in[18];
    const float* clfb = (const float*)d_in[19];
    float* outp = (float*)d_out;

    char* w = (char*)d_ws;
    size_t o = 0;
    auto alloc = [&](size_t bytes) {
        char* p = w + o;
        o = (o + bytes + 255) & ~(size_t)255;
        return p;
    };
    int* cnt    = (int*)alloc((size_t)NN * 4);        // doubles as cursor
    int* offs   = (int*)alloc((size_t)(NN + 1) * 4);
    int* csr    = (int*)alloc((size_t)(EE + NN) * 4);
    float* xl   = (float*)alloc((size_t)NN * HC * 4);
    float* xr   = (float*)alloc((size_t)NN * HC * 4);
    float* h0   = (float*)alloc((size_t)NN * HC * 4);
    float* h1   = (float*)alloc((size_t)NN * HC * 4);
    float* gsum = (float*)alloc(HC * 4);

    // CSR by destination (rebuilt every call; graph-capture safe, all on stream)
    k_zero<<<(NN + 255) / 256, 256, 0, stream>>>(cnt, NN);
    k_count<<<(EE + 255) / 256, 256, 0, stream>>>(ei, cnt);
    k_scan<<<1, 1024, 0, stream>>>(cnt, offs);
    k_selfloop<<<(NN + 255) / 256, 256, 0, stream>>>(offs, cnt, csr);
    k_fill<<<(EE + 255) / 256, 256, 0, stream>>>(ei, cnt, csr);

    const float* hin = x;
    float* houts[4] = {h0, h1, h0, h1};
    for (int l = 0; l < 4; ++l) {
        int K = (l == 0) ? 768 : HC;
        dim3 g((NN + BM - 1) / BM, 4);
        k_gemm<<<g, 256, 0, stream>>>(hin, K, Wl[l], Wr[l], xl, xr);
        k_edge<<<NN, 128, 0, stream>>>(xl, xr, att[l], bia[l], offs, csr,
                                       houts[l], (l < 3) ? 1 : 0);
        hin = houts[l];
    }

    k_zero<<<1, 128, 0, stream>>>((int*)gsum, HC);
    k_colsum<<<512, 128, 0, stream>>>(h1, gsum);
    k_clf<<<1, 64, 0, stream>>>(gsum, clfW, clfb, outp);
}

// Round 2
// 596.226 us; speedup vs baseline: 1.7988x; 1.7988x over previous
//
#include <hip/hip_runtime.h>
#include <hip/hip_bf16.h>

#define NN 50000
#define EE 640000
#define HC 128
#define NB1 196   // ceil(NN/256)

typedef short bf16x8 __attribute__((ext_vector_type(8)));
typedef float f32x4 __attribute__((ext_vector_type(4)));
typedef unsigned short u16;

__device__ __forceinline__ u16 f2b(float f) {   // RN-even
    unsigned u = __float_as_uint(f);
    unsigned r = u + 0x7FFFu + ((u >> 16) & 1u);
    return (u16)(r >> 16);
}
__device__ __forceinline__ float b2f(u16 h) {
    return __uint_as_float(((unsigned)h) << 16);
}

__device__ __forceinline__ void gload_lds16(const void* g, void* l) {
    __builtin_amdgcn_global_load_lds((const __attribute__((address_space(1))) void*)g,
                                     (__attribute__((address_space(3))) void*)l, 16, 0, 0);
}

// 32-lane-group sum, all lanes get result: 4 VALU-DPP xor{1,2,7,8} + ds_swizzle xor16
__device__ __forceinline__ float red32(float x) {
    x += __int_as_float(__builtin_amdgcn_update_dpp(0, __float_as_int(x), 0xB1, 0xF, 0xF, true));
    x += __int_as_float(__builtin_amdgcn_update_dpp(0, __float_as_int(x), 0x4E, 0xF, 0xF, true));
    x += __int_as_float(__builtin_amdgcn_update_dpp(0, __float_as_int(x), 0x141, 0xF, 0xF, true));
    x += __int_as_float(__builtin_amdgcn_update_dpp(0, __float_as_int(x), 0x128, 0xF, 0xF, true));
    x += __int_as_float(__builtin_amdgcn_ds_swizzle(__float_as_int(x), 0x401F));
    return x;
}

// ---------------- CSR build ----------------

__global__ void k_zero(int* __restrict__ p, int n) {
    int i = blockIdx.x * blockDim.x + threadIdx.x;
    if (i < n) p[i] = 0;
}

__global__ void k_count(const int* __restrict__ ei, int* __restrict__ cnt) {
    int e = blockIdx.x * blockDim.x + threadIdx.x;
    if (e < EE) atomicAdd(&cnt[ei[EE + e]], 1);
}

__global__ void k_bsum(const int* __restrict__ cnt, int* __restrict__ bsum) {
    __shared__ int sd[256];
    int b = blockIdx.x, t = threadIdx.x, i = b * 256 + t;
    sd[t] = (i < NN) ? cnt[i] + 1 : 0;
    __syncthreads();
    for (int o = 128; o; o >>= 1) { if (t < o) sd[t] += sd[t + o]; __syncthreads(); }
    if (!t) bsum[b] = sd[0];
}

__global__ void k_bscan(const int* __restrict__ bsum, int* __restrict__ bex,
                        int* __restrict__ offs) {
    __shared__ int sd[256];
    int t = threadIdx.x;
    int v = (t < NB1) ? bsum[t] : 0;
    sd[t] = v; __syncthreads();
    for (int o = 1; o < 256; o <<= 1) {
        int u = (t >= o) ? sd[t - o] : 0;
        __syncthreads(); sd[t] += u; __syncthreads();
    }
    bex[t] = sd[t] - v;
    if (t == NB1 - 1) offs[NN] = sd[t];
}

__global__ void k_offs(const int* __restrict__ cnt, const int* __restrict__ bex,
                       int* __restrict__ offs) {
    __shared__ int sd[256];
    int b = blockIdx.x, t = threadIdx.x, i = b * 256 + t;
    int v = (i < NN) ? cnt[i] + 1 : 0;
    sd[t] = v; __syncthreads();
    for (int o = 1; o < 256; o <<= 1) {
        int u = (t >= o) ? sd[t - o] : 0;
        __syncthreads(); sd[t] += u; __syncthreads();
    }
    if (i < NN) offs[i] = bex[b] + sd[t] - v;
}

__global__ void k_selfloop(const int* __restrict__ offs, int* __restrict__ cursor,
                           int* __restrict__ csr) {
    int i = blockIdx.x * blockDim.x + threadIdx.x;
    if (i < NN) { int o = offs[i]; csr[o] = i; cursor[i] = o + 1; }
}

__global__ void k_fill(const int* __restrict__ ei, int* __restrict__ cursor,
                       int* __restrict__ csr) {
    int e = blockIdx.x * blockDim.x + threadIdx.x;
    if (e < EE) {
        int s = ei[e], d = ei[EE + e];
        int pos = atomicAdd(&cursor[d], 1);
        csr[pos] = s;
    }
}

// ---------------- W cast+transpose: Wt[256][K] bf16, cols 0-127 = Wl, 128-255 = Wr ----------------

__global__ void k_castw(const float* __restrict__ Wl, const float* __restrict__ Wr,
                        u16* __restrict__ Wt, int K) {
    int idx = blockIdx.x * 256 + threadIdx.x;   // = c*K + k
    if (idx < 256 * K) {
        int c = idx / K, k = idx - c * K;
        float v = (c < 128) ? Wl[k * 128 + c] : Wr[k * 128 + (c - 128)];
        Wt[idx] = f2b(v);
    }
}

// ---------------- MFMA bf16 GEMM ----------------
// out[N,256] = A[N,K] @ Wt^T ; grid (ceil(N/128), 2); y=0 -> xlb (bf16), y=1 -> xr (fp32)
// LDS tiles As[128][32], Bs[128][32] bf16, 16B-chunk XOR swizzle: phys = logical ^ ((row>>1)&3)

template<int K, bool F32A>
__global__ __launch_bounds__(256)
void k_gemm(const void* __restrict__ Ag, const u16* __restrict__ Wt,
            u16* __restrict__ xlb, float* __restrict__ xr) {
    __shared__ __align__(16) u16 As[128 * 32];
    __shared__ __align__(16) u16 Bs[128 * 32];
    const int tid = threadIdx.x;
    const int wv = tid >> 6, ln = tid & 63;
    const int wr = wv >> 1, wc = wv & 1;
    const int m0 = blockIdx.x * 128;
    const int isXr = blockIdx.y;
    const int nb0 = isXr * 128;

    f32x4 acc[4][4] = {};

    for (int k0 = 0; k0 < K; k0 += 32) {
        if constexpr (F32A) {
            // reg-stage fp32 -> bf16 with swizzled ds_write
            const float* A = (const float*)Ag;
            int r = tid >> 1, hh = tid & 1;
            int rg = m0 + r; if (rg >= NN) rg = 0;
            int s = (r >> 1) & 3;
            #pragma unroll
            for (int q = 0; q < 2; ++q) {
                int lc = hh * 2 + q;
                const float* src = A + (size_t)rg * K + k0 + lc * 8;
                float4 f0 = *(const float4*)(src);
                float4 f1 = *(const float4*)(src + 4);
                bf16x8 v;
                v[0] = (short)f2b(f0.x); v[1] = (short)f2b(f0.y);
                v[2] = (short)f2b(f0.z); v[3] = (short)f2b(f0.w);
                v[4] = (short)f2b(f1.x); v[5] = (short)f2b(f1.y);
                v[6] = (short)f2b(f1.z); v[7] = (short)f2b(f1.w);
                *(bf16x8*)&As[r * 32 + ((lc ^ s) * 8)] = v;
            }
        } else {
            const u16* A = (const u16*)Ag;
            #pragma unroll
            for (int q = 0; q < 2; ++q) {
                int seg = wv * 2 + q;
                int r = seg * 16 + (ln >> 2);
                int pc = ln & 3;
                int rg = m0 + r; if (rg >= NN) rg = 0;
                int lc = pc ^ ((r >> 1) & 3);
                gload_lds16(A + (size_t)rg * K + k0 + lc * 8, &As[seg * 512]);
            }
        }
        #pragma unroll
        for (int q = 0; q < 2; ++q) {
            int seg = wv * 2 + q;
            int c = seg * 16 + (ln >> 2);
            int pc = ln & 3;
            int lc = pc ^ ((c >> 1) & 3);
            gload_lds16(Wt + (size_t)(nb0 + c) * K + k0 + lc * 8, &Bs[seg * 512]);
        }
        asm volatile("s_waitcnt vmcnt(0)" ::: "memory");
        __syncthreads();

        const int lrow = ln & 15;
        const int g = ln >> 4;
        bf16x8 af[4], bfr[4];
        #pragma unroll
        for (int f = 0; f < 4; ++f) {
            int r = wr * 64 + f * 16 + lrow;
            af[f] = *(const bf16x8*)&As[r * 32 + ((g ^ ((r >> 1) & 3)) * 8)];
            int c = wc * 64 + f * 16 + lrow;
            bfr[f] = *(const bf16x8*)&Bs[c * 32 + ((g ^ ((c >> 1) & 3)) * 8)];
        }
        #pragma unroll
        for (int i = 0; i < 4; ++i)
            #pragma unroll
            for (int j = 0; j < 4; ++j)
                acc[i][j] = __builtin_amdgcn_mfma_f32_16x16x32_bf16(af[i], bfr[j], acc[i][j], 0, 0, 0);
        __syncthreads();
    }

    const int crow = m0 + wr * 64 + ((ln >> 4) << 2);
    const int ccol = wc * 64 + (ln & 15);
    #pragma unroll
    for (int i = 0; i < 4; ++i)
        #pragma unroll
        for (int j = 0; j < 4; ++j)
            #pragma unroll
            for (int rr = 0; rr < 4; ++rr) {
                int row = crow + i * 16 + rr;
                int col = ccol + j * 16;
                if (row < NN) {
                    if (!isXr) xlb[(size_t)row * HC + col] = f2b(acc[i][j][rr]);
                    else       xr[(size_t)row * HC + col]  = acc[i][j][rr];
                }
            }
}

// ---------------- per-node online-softmax GATv2 aggregation ----------------

__global__ __launch_bounds__(128)
void k_edge(const u16* __restrict__ xlb, const float* __restrict__ xr,
            const float* __restrict__ att, const float* __restrict__ bias,
            const int* __restrict__ offs, const int* __restrict__ csr,
            u16* __restrict__ outb, float* __restrict__ outf, int relu) {
    int i = blockIdx.x, t = threadIdx.x;
    float xri = xr[(size_t)i * HC + t];
    float at = att[t];
    int beg = offs[i], end = offs[i + 1];

    float mA = -3.0e38f, sA = 0.f, aA = 0.f;
    float mB = -3.0e38f, sB = 0.f, aB = 0.f;

    for (int p = beg; p < end; p += 2) {
        int ja = csr[p];
        bool hb = (p + 1 < end);
        int jb = hb ? csr[p + 1] : ja;
        float va = b2f(xlb[(size_t)ja * HC + t]);
        float vb = b2f(xlb[(size_t)jb * HC + t]);
        float ua = va + xri; ua = (ua > 0.f) ? ua : 0.2f * ua; ua *= at;
        float ub = vb + xri; ub = (ub > 0.f) ? ub : 0.2f * ub; ub *= at;
        ua = red32(ua);
        ub = red32(ub);
        { float mn = fmaxf(mA, ua); float c = __expf(mA - mn), w = __expf(ua - mn);
          sA = sA * c + w; aA = aA * c + w * va; mA = mn; }
        if (hb) {
          float mn = fmaxf(mB, ub); float c = __expf(mB - mn), w = __expf(ub - mn);
          sB = sB * c + w; aB = aB * c + w * vb; mB = mn; }
    }
    float mm = fmaxf(mA, mB);
    float cA = __expf(mA - mm), cB = __expf(mB - mm);
    float s = sA * cA + sB * cB;
    float acc = aA * cA + aB * cB;
    float o = acc / (s + 1e-16f) + bias[t];
    if (relu) o = fmaxf(o, 0.f);
    if (outb) outb[(size_t)i * HC + t] = f2b(o);
    if (outf) outf[(size_t)i * HC + t] = o;
}

// ---------------- tail ----------------

__global__ void k_colsum(const float* __restrict__ h, float* __restrict__ part) {
    int b = blockIdx.x, t = threadIdx.x;   // grid 128 x 128
    float s = 0.f;
    for (int i = b; i < NN; i += 128) s += h[(size_t)i * HC + t];
    part[b * HC + t] = s;
}

__global__ void k_clf(const float* __restrict__ part, const float* __restrict__ W,
                      const float* __restrict__ bcls, float* __restrict__ out) {
    __shared__ float v[HC];
    int t = threadIdx.x;   // 128
    float s = 0.f;
    for (int b = 0; b < 128; ++b) s += part[b * HC + t];
    v[t] = s * (1.f / (float)NN);
    __syncthreads();
    if (t < 2) {
        float r = 0.f;
        for (int k = 0; k < HC; ++k) r += v[k] * W[k * 2 + t];
        out[t] = r + bcls[t];
    }
}

// ---------------- launch ----------------

extern "C" void kernel_launch(void* const* d_in, const int* in_sizes, int n_in,
                              void* d_out, int out_size, void* d_ws, size_t ws_size,
                              hipStream_t stream) {
    const float* x = (const float*)d_in[0];
    const int* ei = (const int*)d_in[1];
    const float *Wl[4], *Wr[4], *att[4], *bia[4];
    for (int l = 0; l < 4; ++l) {
        Wl[l] = (const float*)d_in[2 + 4 * l];
        Wr[l] = (const float*)d_in[3 + 4 * l];
        att[l] = (const float*)d_in[4 + 4 * l];
        bia[l] = (const float*)d_in[5 + 4 * l];
    }
    const float* clfW = (const float*)d_in[18];
    const float* clfb = (const float*)d_in[19];
    float* outp = (float*)d_out;

    char* w = (char*)d_ws;
    size_t o = 0;
    auto alloc = [&](size_t bytes) {
        char* p = w + o;
        o = (o + bytes + 255) & ~(size_t)255;
        return p;
    };
    int* cnt   = (int*)alloc((size_t)NN * 4);
    int* offs  = (int*)alloc((size_t)(NN + 1) * 4);
    int* csr   = (int*)alloc((size_t)(EE + NN) * 4);
    int* bsum  = (int*)alloc((size_t)NB1 * 4);
    int* bex   = (int*)alloc(256 * 4);
    u16* Wt    = (u16*)alloc((size_t)256 * 768 * 2);
    u16* xlb   = (u16*)alloc((size_t)NN * HC * 2);
    float* xr  = (float*)alloc((size_t)NN * HC * 4);
    u16* hb0   = (u16*)alloc((size_t)NN * HC * 2);
    u16* hb1   = (u16*)alloc((size_t)NN * HC * 2);
    float* hfin = (float*)alloc((size_t)NN * HC * 4);
    float* part = (float*)alloc((size_t)128 * HC * 4);

    // CSR by destination
    k_zero<<<NB1, 256, 0, stream>>>(cnt, NN);
    k_count<<<(EE + 255) / 256, 256, 0, stream>>>(ei, cnt);
    k_bsum<<<NB1, 256, 0, stream>>>(cnt, bsum);
    k_bscan<<<1, 256, 0, stream>>>(bsum, bex, offs);
    k_offs<<<NB1, 256, 0, stream>>>(cnt, bex, offs);
    k_selfloop<<<NB1, 256, 0, stream>>>(offs, cnt, csr);
    k_fill<<<(EE + 255) / 256, 256, 0, stream>>>(ei, cnt, csr);

    dim3 gg(391, 2);
    const u16* hb_in = nullptr;
    u16* hbb[2] = {hb0, hb1};
    for (int l = 0; l < 4; ++l) {
        int K = (l == 0) ? 768 : HC;
        k_castw<<<(256 * K + 255) / 256, 256, 0, stream>>>(Wl[l], Wr[l], Wt, K);
        if (l == 0) k_gemm<768, true ><<<gg, 256, 0, stream>>>((const void*)x, Wt, xlb, xr);
        else        k_gemm<128, false><<<gg, 256, 0, stream>>>((const void*)hb_in, Wt, xlb, xr);
        u16* ob = (l < 3) ? hbb[l & 1] : nullptr;
        float* of = (l == 3) ? hfin : nullptr;
        k_edge<<<NN, 128, 0, stream>>>(xlb, xr, att[l], bia[l], offs, csr, ob, of, (l < 3) ? 1 : 0);
        hb_in = ob;
    }

    k_colsum<<<128, 128, 0, stream>>>(hfin, part);
    k_clf<<<1, 128, 0, stream>>>(part, clfW, clfb, outp);
}

// Round 3
// 574.830 us; speedup vs baseline: 1.8657x; 1.0372x over previous
//
#include <hip/hip_runtime.h>
#include <hip/hip_bf16.h>

#define NN 50000
#define EE 640000
#define HC 128
#define NB1 196   // ceil(NN/256)

typedef short bf16x8 __attribute__((ext_vector_type(8)));
typedef float f32x4 __attribute__((ext_vector_type(4)));
typedef unsigned short u16;

__device__ __forceinline__ u16 f2b(float f) {   // RN-even
    unsigned u = __float_as_uint(f);
    unsigned r = u + 0x7FFFu + ((u >> 16) & 1u);
    return (u16)(r >> 16);
}
__device__ __forceinline__ float b2f(u16 h) {
    return __uint_as_float(((unsigned)h) << 16);
}

__device__ __forceinline__ void gload_lds16(const void* g, void* l) {
    __builtin_amdgcn_global_load_lds((const __attribute__((address_space(1))) void*)g,
                                     (__attribute__((address_space(3))) void*)l, 16, 0, 0);
}

// 32-lane-group sum, all lanes get result: 4 VALU-DPP xor{1,2,7,8} + ds_swizzle xor16
__device__ __forceinline__ float red32(float x) {
    x += __int_as_float(__builtin_amdgcn_update_dpp(0, __float_as_int(x), 0xB1, 0xF, 0xF, true));
    x += __int_as_float(__builtin_amdgcn_update_dpp(0, __float_as_int(x), 0x4E, 0xF, 0xF, true));
    x += __int_as_float(__builtin_amdgcn_update_dpp(0, __float_as_int(x), 0x141, 0xF, 0xF, true));
    x += __int_as_float(__builtin_amdgcn_update_dpp(0, __float_as_int(x), 0x128, 0xF, 0xF, true));
    x += __int_as_float(__builtin_amdgcn_ds_swizzle(__float_as_int(x), 0x401F));
    return x;
}

// ---------------- CSR build ----------------

__global__ void k_zero(int* __restrict__ p, int n) {
    int i = blockIdx.x * blockDim.x + threadIdx.x;
    if (i < n) p[i] = 0;
}

__global__ void k_count(const int* __restrict__ ei, int* __restrict__ cnt) {
    int e = blockIdx.x * blockDim.x + threadIdx.x;
    if (e < EE) atomicAdd(&cnt[ei[EE + e]], 1);
}

__global__ void k_bsum(const int* __restrict__ cnt, int* __restrict__ bsum) {
    __shared__ int sd[256];
    int b = blockIdx.x, t = threadIdx.x, i = b * 256 + t;
    sd[t] = (i < NN) ? cnt[i] + 1 : 0;
    __syncthreads();
    for (int o = 128; o; o >>= 1) { if (t < o) sd[t] += sd[t + o]; __syncthreads(); }
    if (!t) bsum[b] = sd[0];
}

__global__ void k_bscan(const int* __restrict__ bsum, int* __restrict__ bex,
                        int* __restrict__ offs) {
    __shared__ int sd[256];
    int t = threadIdx.x;
    int v = (t < NB1) ? bsum[t] : 0;
    sd[t] = v; __syncthreads();
    for (int o = 1; o < 256; o <<= 1) {
        int u = (t >= o) ? sd[t - o] : 0;
        __syncthreads(); sd[t] += u; __syncthreads();
    }
    bex[t] = sd[t] - v;
    if (t == NB1 - 1) offs[NN] = sd[t];
}

__global__ void k_offs(const int* __restrict__ cnt, const int* __restrict__ bex,
                       int* __restrict__ offs) {
    __shared__ int sd[256];
    int b = blockIdx.x, t = threadIdx.x, i = b * 256 + t;
    int v = (i < NN) ? cnt[i] + 1 : 0;
    sd[t] = v; __syncthreads();
    for (int o = 1; o < 256; o <<= 1) {
        int u = (t >= o) ? sd[t - o] : 0;
        __syncthreads(); sd[t] += u; __syncthreads();
    }
    if (i < NN) offs[i] = bex[b] + sd[t] - v;
}

__global__ void k_selfloop(const int* __restrict__ offs, int* __restrict__ cursor,
                           int* __restrict__ csr) {
    int i = blockIdx.x * blockDim.x + threadIdx.x;
    if (i < NN) { int o = offs[i]; csr[o] = i; cursor[i] = o + 1; }
}

__global__ void k_fill(const int* __restrict__ ei, int* __restrict__ cursor,
                       int* __restrict__ csr) {
    int e = blockIdx.x * blockDim.x + threadIdx.x;
    if (e < EE) {
        int s = ei[e], d = ei[EE + e];
        int pos = atomicAdd(&cursor[d], 1);
        csr[pos] = s;
    }
}

// ---------------- W cast+transpose: Wt[256][K] bf16, rows 0-127 = Wl cols, 128-255 = Wr cols ----------------

__global__ void k_castw(const float* __restrict__ Wl, const float* __restrict__ Wr,
                        u16* __restrict__ Wt, int K) {
    int idx = blockIdx.x * 256 + threadIdx.x;   // = c*K + k
    if (idx < 256 * K) {
        int c = idx / K, k = idx - c * K;
        float v = (c < 128) ? Wl[k * 128 + c] : Wr[k * 128 + (c - 128)];
        Wt[idx] = f2b(v);
    }
}

// ---------------- MFMA bf16 GEMM ----------------
// xb[N][256] = A[N,K] @ Wt^T (bf16 out). Tile 64 rows x 256 cols, 4 waves (64x64 each), BK=64.
// LDS: As[64][64] u16, Bs[256][64] u16; 16B-chunk XOR swizzle phys = logical ^ (row&7).

template<int K, bool F32A>
__global__ __launch_bounds__(256)
void k_gemm(const void* __restrict__ Ag, const u16* __restrict__ Wt,
            u16* __restrict__ xb) {
    __shared__ __align__(16) u16 As[64 * 64];
    __shared__ __align__(16) u16 Bs[256 * 64];
    const int tid = threadIdx.x;
    const int wv = tid >> 6, ln = tid & 63;
    const int m0 = blockIdx.x * 64;
    const int lrow = ln & 15, g = ln >> 4;

    f32x4 acc[4][4] = {};

    const float* Af = (const float*)Ag;
    const u16* Ab = (const u16*)Ag;
    const int arow = tid >> 2, aq = tid & 3;
    int arg = m0 + arow; if (arg >= NN) arg = 0;
    float4 ra0, ra1, ra2, ra3;

    if constexpr (F32A) {
        const float* src = Af + (size_t)arg * K + aq * 16;
        ra0 = *(const float4*)(src);
        ra1 = *(const float4*)(src + 4);
        ra2 = *(const float4*)(src + 8);
        ra3 = *(const float4*)(src + 12);
    }

    constexpr int NSTEP = K / 64;
    for (int ks = 0; ks < NSTEP; ++ks) {
        if constexpr (F32A) {
            const int s = arow & 7;
            bf16x8 v0, v1;
            v0[0] = (short)f2b(ra0.x); v0[1] = (short)f2b(ra0.y);
            v0[2] = (short)f2b(ra0.z); v0[3] = (short)f2b(ra0.w);
            v0[4] = (short)f2b(ra1.x); v0[5] = (short)f2b(ra1.y);
            v0[6] = (short)f2b(ra1.z); v0[7] = (short)f2b(ra1.w);
            v1[0] = (short)f2b(ra2.x); v1[1] = (short)f2b(ra2.y);
            v1[2] = (short)f2b(ra2.z); v1[3] = (short)f2b(ra2.w);
            v1[4] = (short)f2b(ra3.x); v1[5] = (short)f2b(ra3.y);
            v1[6] = (short)f2b(ra3.z); v1[7] = (short)f2b(ra3.w);
            *(bf16x8*)&As[arow * 64 + (((aq * 2) ^ s) * 8)] = v0;
            *(bf16x8*)&As[arow * 64 + (((aq * 2 + 1) ^ s) * 8)] = v1;
        } else {
            #pragma unroll
            for (int q = 0; q < 2; ++q) {
                int r8 = (wv * 2 + q) * 8;
                int row = r8 + (ln >> 3);
                int lc = (ln & 7) ^ (row & 7);
                int rg = m0 + row; if (rg >= NN) rg = 0;
                gload_lds16(Ab + (size_t)rg * K + ks * 64 + lc * 8, &As[r8 * 64]);
            }
        }
        #pragma unroll
        for (int q = 0; q < 8; ++q) {
            int r8 = (wv * 8 + q) * 8;
            int row = r8 + (ln >> 3);
            int lc = (ln & 7) ^ (row & 7);
            gload_lds16(Wt + (size_t)row * K + ks * 64 + lc * 8, &Bs[r8 * 64]);
        }
        __syncthreads();   // drains vmcnt (gload_lds) + lgkmcnt (ds_write)

        if constexpr (F32A) {
            if (ks + 1 < NSTEP) {   // T14: issue next tile's loads, consume after next barrier
                const float* src = Af + (size_t)arg * K + (ks + 1) * 64 + aq * 16;
                ra0 = *(const float4*)(src);
                ra1 = *(const float4*)(src + 4);
                ra2 = *(const float4*)(src + 8);
                ra3 = *(const float4*)(src + 12);
            }
        }

        #pragma unroll
        for (int kk = 0; kk < 2; ++kk) {
            bf16x8 af[4], bfr[4];
            #pragma unroll
            for (int f = 0; f < 4; ++f) {
                int r = f * 16 + lrow;
                af[f] = *(const bf16x8*)&As[r * 64 + (((kk * 4 + g) ^ (r & 7)) * 8)];
                int c = wv * 64 + f * 16 + lrow;
                bfr[f] = *(const bf16x8*)&Bs[c * 64 + (((kk * 4 + g) ^ (c & 7)) * 8)];
            }
            #pragma unroll
            for (int i = 0; i < 4; ++i)
                #pragma unroll
                for (int j = 0; j < 4; ++j)
                    acc[i][j] = __builtin_amdgcn_mfma_f32_16x16x32_bf16(af[i], bfr[j], acc[i][j], 0, 0, 0);
        }
        __syncthreads();
    }

    const int crow0 = m0 + (g << 2);
    const int ccol0 = wv * 64 + lrow;
    #pragma unroll
    for (int i = 0; i < 4; ++i)
        #pragma unroll
        for (int rr = 0; rr < 4; ++rr) {
            int row = crow0 + i * 16 + rr;
            if (row < NN) {
                #pragma unroll
                for (int j = 0; j < 4; ++j)
                    xb[(size_t)row * 256 + ccol0 + j * 16] = f2b(acc[i][j][rr]);
            }
        }
}

// ---------------- per-node online-softmax GATv2 aggregation ----------------
// xb[i][0:128] = xl_i (bf16), xb[i][128:256] = xr_i (bf16)

__global__ __launch_bounds__(128)
void k_edge(const u16* __restrict__ xb, const float* __restrict__ att,
            const float* __restrict__ bias, const int* __restrict__ offs,
            const int* __restrict__ csr, u16* __restrict__ outb,
            float* __restrict__ outf, int relu) {
    int i = blockIdx.x, t = threadIdx.x;
    float xri = b2f(xb[(size_t)i * 256 + 128 + t]);
    float at = att[t];
    int beg = offs[i], end = offs[i + 1];

    float mA = -3.0e38f, sA = 0.f, aA = 0.f;
    float mB = -3.0e38f, sB = 0.f, aB = 0.f;

    for (int p = beg; p < end; p += 2) {
        int ja = csr[p];
        bool hb = (p + 1 < end);
        int jb = hb ? csr[p + 1] : ja;
        float va = b2f(xb[(size_t)ja * 256 + t]);
        float vb = b2f(xb[(size_t)jb * 256 + t]);
        float ua = va + xri; ua = (ua > 0.f) ? ua : 0.2f * ua; ua *= at;
        float ub = vb + xri; ub = (ub > 0.f) ? ub : 0.2f * ub; ub *= at;
        ua = red32(ua);
        ub = red32(ub);
        { float mn = fmaxf(mA, ua); float c = __expf(mA - mn), w = __expf(ua - mn);
          sA = sA * c + w; aA = aA * c + w * va; mA = mn; }
        if (hb) {
          float mn = fmaxf(mB, ub); float c = __expf(mB - mn), w = __expf(ub - mn);
          sB = sB * c + w; aB = aB * c + w * vb; mB = mn; }
    }
    float mm = fmaxf(mA, mB);
    float cA = __expf(mA - mm), cB = __expf(mB - mm);
    float s = sA * cA + sB * cB;
    float acc = aA * cA + aB * cB;
    float o = acc / (s + 1e-16f) + bias[t];
    if (relu) o = fmaxf(o, 0.f);
    if (outb) outb[(size_t)i * HC + t] = f2b(o);
    if (outf) outf[(size_t)i * HC + t] = o;
}

// ---------------- tail ----------------

__global__ void k_colsum(const float* __restrict__ h, float* __restrict__ part) {
    int b = blockIdx.x, t = threadIdx.x;   // grid 128 x 128
    float s = 0.f;
    for (int i = b; i < NN; i += 128) s += h[(size_t)i * HC + t];
    part[b * HC + t] = s;
}

__global__ void k_clf(const float* __restrict__ part, const float* __restrict__ W,
                      const float* __restrict__ bcls, float* __restrict__ out) {
    __shared__ float v[HC];
    int t = threadIdx.x;   // 128
    float s = 0.f;
    for (int b = 0; b < 128; ++b) s += part[b * HC + t];
    v[t] = s * (1.f / (float)NN);
    __syncthreads();
    if (t < 2) {
        float r = 0.f;
        for (int k = 0; k < HC; ++k) r += v[k] * W[k * 2 + t];
        out[t] = r + bcls[t];
    }
}

// ---------------- launch ----------------

extern "C" void kernel_launch(void* const* d_in, const int* in_sizes, int n_in,
                              void* d_out, int out_size, void* d_ws, size_t ws_size,
                              hipStream_t stream) {
    const float* x = (const float*)d_in[0];
    const int* ei = (const int*)d_in[1];
    const float *Wl[4], *Wr[4], *att[4], *bia[4];
    for (int l = 0; l < 4; ++l) {
        Wl[l] = (const float*)d_in[2 + 4 * l];
        Wr[l] = (const float*)d_in[3 + 4 * l];
        att[l] = (const float*)d_in[4 + 4 * l];
        bia[l] = (const float*)d_in[5 + 4 * l];
    }
    const float* clfW = (const float*)d_in[18];
    const float* clfb = (const float*)d_in[19];
    float* outp = (float*)d_out;

    char* w = (char*)d_ws;
    size_t o = 0;
    auto alloc = [&](size_t bytes) {
        char* p = w + o;
        o = (o + bytes + 255) & ~(size_t)255;
        return p;
    };
    int* cnt   = (int*)alloc((size_t)NN * 4);
    int* offs  = (int*)alloc((size_t)(NN + 1) * 4);
    int* csr   = (int*)alloc((size_t)(EE + NN) * 4);
    int* bsum  = (int*)alloc((size_t)NB1 * 4);
    int* bex   = (int*)alloc(256 * 4);
    u16* Wt    = (u16*)alloc((size_t)256 * 768 * 2);
    u16* xb    = (u16*)alloc((size_t)NN * 256 * 2);
    u16* hb0   = (u16*)alloc((size_t)NN * HC * 2);
    u16* hb1   = (u16*)alloc((size_t)NN * HC * 2);
    float* hfin = (float*)alloc((size_t)NN * HC * 4);
    float* part = (float*)alloc((size_t)128 * HC * 4);

    // CSR by destination
    k_zero<<<NB1, 256, 0, stream>>>(cnt, NN);
    k_count<<<(EE + 255) / 256, 256, 0, stream>>>(ei, cnt);
    k_bsum<<<NB1, 256, 0, stream>>>(cnt, bsum);
    k_bscan<<<1, 256, 0, stream>>>(bsum, bex, offs);
    k_offs<<<NB1, 256, 0, stream>>>(cnt, bex, offs);
    k_selfloop<<<NB1, 256, 0, stream>>>(offs, cnt, csr);
    k_fill<<<(EE + 255) / 256, 256, 0, stream>>>(ei, cnt, csr);

    const int GB = (NN + 63) / 64;   // 782
    const u16* hb_in = nullptr;
    u16* hbb[2] = {hb0, hb1};
    for (int l = 0; l < 4; ++l) {
        int K = (l == 0) ? 768 : HC;
        k_castw<<<(256 * K + 255) / 256, 256, 0, stream>>>(Wl[l], Wr[l], Wt, K);
        if (l == 0) k_gemm<768, true ><<<GB, 256, 0, stream>>>((const void*)x, Wt, xb);
        else        k_gemm<128, false><<<GB, 256, 0, stream>>>((const void*)hb_in, Wt, xb);
        u16* ob = (l < 3) ? hbb[l & 1] : nullptr;
        float* of = (l == 3) ? hfin : nullptr;
        k_edge<<<NN, 128, 0, stream>>>(xb, att[l], bia[l], offs, csr, ob, of, (l < 3) ? 1 : 0);
        hb_in = ob;
    }

    k_colsum<<<128, 128, 0, stream>>>(hfin, part);
    k_clf<<<1, 128, 0, stream>>>(part, clfW, clfb, outp);
}

// Round 4
// 498.044 us; speedup vs baseline: 2.1534x; 1.1542x over previous
//
#include <hip/hip_runtime.h>
#include <hip/hip_bf16.h>

#define NN 50000
#define EE 640000
#define HC 128
#define NB1 196   // ceil(NN/256)

typedef short bf16x8 __attribute__((ext_vector_type(8)));
typedef float f32x4 __attribute__((ext_vector_type(4)));
typedef unsigned short u16;

__device__ __forceinline__ u16 f2b(float f) {   // RN-even
    unsigned u = __float_as_uint(f);
    unsigned r = u + 0x7FFFu + ((u >> 16) & 1u);
    return (u16)(r >> 16);
}
__device__ __forceinline__ float b2f(u16 h) {
    return __uint_as_float(((unsigned)h) << 16);
}

__device__ __forceinline__ void gload_lds16(const void* g, void* l) {
    __builtin_amdgcn_global_load_lds((const __attribute__((address_space(1))) void*)g,
                                     (__attribute__((address_space(3))) void*)l, 16, 0, 0);
}

// sum across each 16-lane row, all lanes get result: pure DPP (no LDS op)
// xor1 (quad_perm[1,0,3,2]), xor2 (quad_perm[2,3,0,1]), half_mirror (xor7 on 8-uniform),
// row_ror:8 (combines the two 8-halves of a 16-row)
__device__ __forceinline__ float red16(float x) {
    x += __int_as_float(__builtin_amdgcn_update_dpp(0, __float_as_int(x), 0xB1, 0xF, 0xF, true));
    x += __int_as_float(__builtin_amdgcn_update_dpp(0, __float_as_int(x), 0x4E, 0xF, 0xF, true));
    x += __int_as_float(__builtin_amdgcn_update_dpp(0, __float_as_int(x), 0x141, 0xF, 0xF, true));
    x += __int_as_float(__builtin_amdgcn_update_dpp(0, __float_as_int(x), 0x128, 0xF, 0xF, true));
    return x;
}

// ---------------- CSR build ----------------

__global__ void k_zero(int* __restrict__ p, int n) {
    int i = blockIdx.x * blockDim.x + threadIdx.x;
    if (i < n) p[i] = 0;
}

__global__ void k_count(const int* __restrict__ ei, int* __restrict__ cnt,
                        float* __restrict__ gsum) {
    int e = blockIdx.x * blockDim.x + threadIdx.x;
    if (e < EE) atomicAdd(&cnt[ei[EE + e]], 1);
    if (blockIdx.x == 0 && threadIdx.x < HC) gsum[threadIdx.x] = 0.f;
}

__global__ void k_bsum(const int* __restrict__ cnt, int* __restrict__ bsum) {
    __shared__ int sd[256];
    int b = blockIdx.x, t = threadIdx.x, i = b * 256 + t;
    sd[t] = (i < NN) ? cnt[i] + 1 : 0;
    __syncthreads();
    for (int o = 128; o; o >>= 1) { if (t < o) sd[t] += sd[t + o]; __syncthreads(); }
    if (!t) bsum[b] = sd[0];
}

__global__ void k_bscan(const int* __restrict__ bsum, int* __restrict__ bex,
                        int* __restrict__ offs) {
    __shared__ int sd[256];
    int t = threadIdx.x;
    int v = (t < NB1) ? bsum[t] : 0;
    sd[t] = v; __syncthreads();
    for (int o = 1; o < 256; o <<= 1) {
        int u = (t >= o) ? sd[t - o] : 0;
        __syncthreads(); sd[t] += u; __syncthreads();
    }
    bex[t] = sd[t] - v;
    if (t == NB1 - 1) offs[NN] = sd[t];
}

// offs + self-loop + cursor init fused
__global__ void k_offs(const int* __restrict__ cnt_in, const int* __restrict__ bex,
                       int* __restrict__ offs, int* __restrict__ cursor,
                       int* __restrict__ csr) {
    __shared__ int sd[256];
    int b = blockIdx.x, t = threadIdx.x, i = b * 256 + t;
    int v = (i < NN) ? cnt_in[i] + 1 : 0;
    sd[t] = v; __syncthreads();
    for (int o = 1; o < 256; o <<= 1) {
        int u = (t >= o) ? sd[t - o] : 0;
        __syncthreads(); sd[t] += u; __syncthreads();
    }
    if (i < NN) {
        int o = bex[b] + sd[t] - v;
        offs[i] = o;
        csr[o] = i;          // self loop first
        cursor[i] = o + 1;
    }
}

__global__ void k_fill(const int* __restrict__ ei, int* __restrict__ cursor,
                       int* __restrict__ csr) {
    int e = blockIdx.x * blockDim.x + threadIdx.x;
    if (e < EE) {
        int s = ei[e], d = ei[EE + e];
        int pos = atomicAdd(&cursor[d], 1);
        csr[pos] = s;
    }
}

// ---------------- all-layer W cast+transpose ----------------
// WtAll: [256][768] for L0, then 3 x [256][128]; row c: 0-127 = Wl col c, 128-255 = Wr col c-128

#define WT_L0 196608              // 256*768
#define WT_LX 32768               // 256*128
#define WT_TOT (WT_L0 + 3 * WT_LX)

__global__ void k_castw_all(const float* __restrict__ Wl1, const float* __restrict__ Wr1,
                            const float* __restrict__ Wl2, const float* __restrict__ Wr2,
                            const float* __restrict__ Wl3, const float* __restrict__ Wr3,
                            const float* __restrict__ Wl4, const float* __restrict__ Wr4,
                            u16* __restrict__ WtAll) {
    int gid = blockIdx.x * 256 + threadIdx.x;
    if (gid >= WT_TOT) return;
    const float *Wl, *Wr;
    int idx, K, base;
    if (gid < WT_L0) { Wl = Wl1; Wr = Wr1; idx = gid; K = 768; base = 0; }
    else {
        int r = gid - WT_L0;
        int l = r >> 15; idx = r & (WT_LX - 1); K = 128; base = WT_L0 + l * WT_LX;
        if (l == 0)      { Wl = Wl2; Wr = Wr2; }
        else if (l == 1) { Wl = Wl3; Wr = Wr3; }
        else             { Wl = Wl4; Wr = Wr4; }
    }
    int c = idx / K, k = idx - c * K;
    float v = (c < 128) ? Wl[k * 128 + c] : Wr[k * 128 + (c - 128)];
    WtAll[base + idx] = f2b(v);
}

// ---------------- MFMA bf16 GEMM ----------------
// xb[N][256] = A[N,K] @ Wt^T (bf16 out). Tile 64 rows x 256 cols, 4 waves (64x64 each), BK=64.
// LDS: As[64][64] u16, Bs[256][64] u16; 16B-chunk XOR swizzle phys = logical ^ (row&7).

template<int K, bool F32A>
__global__ __launch_bounds__(256)
void k_gemm(const void* __restrict__ Ag, const u16* __restrict__ Wt,
            u16* __restrict__ xb) {
    __shared__ __align__(16) u16 As[64 * 64];
    __shared__ __align__(16) u16 Bs[256 * 64];
    const int tid = threadIdx.x;
    const int wv = tid >> 6, ln = tid & 63;
    const int m0 = blockIdx.x * 64;
    const int lrow = ln & 15, g = ln >> 4;

    f32x4 acc[4][4] = {};

    const float* Af = (const float*)Ag;
    const u16* Ab = (const u16*)Ag;
    const int arow = tid >> 2, aq = tid & 3;
    int arg = m0 + arow; if (arg >= NN) arg = 0;
    float4 ra0, ra1, ra2, ra3;

    if constexpr (F32A) {
        const float* src = Af + (size_t)arg * K + aq * 16;
        ra0 = *(const float4*)(src);
        ra1 = *(const float4*)(src + 4);
        ra2 = *(const float4*)(src + 8);
        ra3 = *(const float4*)(src + 12);
    }

    constexpr int NSTEP = K / 64;
    for (int ks = 0; ks < NSTEP; ++ks) {
        if constexpr (F32A) {
            const int s = arow & 7;
            bf16x8 v0, v1;
            v0[0] = (short)f2b(ra0.x); v0[1] = (short)f2b(ra0.y);
            v0[2] = (short)f2b(ra0.z); v0[3] = (short)f2b(ra0.w);
            v0[4] = (short)f2b(ra1.x); v0[5] = (short)f2b(ra1.y);
            v0[6] = (short)f2b(ra1.z); v0[7] = (short)f2b(ra1.w);
            v1[0] = (short)f2b(ra2.x); v1[1] = (short)f2b(ra2.y);
            v1[2] = (short)f2b(ra2.z); v1[3] = (short)f2b(ra2.w);
            v1[4] = (short)f2b(ra3.x); v1[5] = (short)f2b(ra3.y);
            v1[6] = (short)f2b(ra3.z); v1[7] = (short)f2b(ra3.w);
            *(bf16x8*)&As[arow * 64 + (((aq * 2) ^ s) * 8)] = v0;
            *(bf16x8*)&As[arow * 64 + (((aq * 2 + 1) ^ s) * 8)] = v1;
        } else {
            #pragma unroll
            for (int q = 0; q < 2; ++q) {
                int r8 = (wv * 2 + q) * 8;
                int row = r8 + (ln >> 3);
                int lc = (ln & 7) ^ (row & 7);
                int rg = m0 + row; if (rg >= NN) rg = 0;
                gload_lds16(Ab + (size_t)rg * K + ks * 64 + lc * 8, &As[r8 * 64]);
            }
        }
        #pragma unroll
        for (int q = 0; q < 8; ++q) {
            int r8 = (wv * 8 + q) * 8;
            int row = r8 + (ln >> 3);
            int lc = (ln & 7) ^ (row & 7);
            gload_lds16(Wt + (size_t)row * K + ks * 64 + lc * 8, &Bs[r8 * 64]);
        }
        __syncthreads();   // drains vmcnt (gload_lds) + lgkmcnt (ds_write)

        if constexpr (F32A) {
            if (ks + 1 < NSTEP) {   // T14: issue next tile's loads, consume after next barrier
                const float* src = Af + (size_t)arg * K + (ks + 1) * 64 + aq * 16;
                ra0 = *(const float4*)(src);
                ra1 = *(const float4*)(src + 4);
                ra2 = *(const float4*)(src + 8);
                ra3 = *(const float4*)(src + 12);
            }
        }

        #pragma unroll
        for (int kk = 0; kk < 2; ++kk) {
            bf16x8 af[4], bfr[4];
            #pragma unroll
            for (int f = 0; f < 4; ++f) {
                int r = f * 16 + lrow;
                af[f] = *(const bf16x8*)&As[r * 64 + (((kk * 4 + g) ^ (r & 7)) * 8)];
                int c = wv * 64 + f * 16 + lrow;
                bfr[f] = *(const bf16x8*)&Bs[c * 64 + (((kk * 4 + g) ^ (c & 7)) * 8)];
            }
            #pragma unroll
            for (int i = 0; i < 4; ++i)
                #pragma unroll
                for (int j = 0; j < 4; ++j)
                    acc[i][j] = __builtin_amdgcn_mfma_f32_16x16x32_bf16(af[i], bfr[j], acc[i][j], 0, 0, 0);
        }
        __syncthreads();
    }

    const int crow0 = m0 + (g << 2);
    const int ccol0 = wv * 64 + lrow;
    #pragma unroll
    for (int i = 0; i < 4; ++i)
        #pragma unroll
        for (int rr = 0; rr < 4; ++rr) {
            int row = crow0 + i * 16 + rr;
            if (row < NN) {
                #pragma unroll
                for (int j = 0; j < 4; ++j)
                    xb[(size_t)row * 256 + ccol0 + j * 16] = f2b(acc[i][j][rr]);
            }
        }
}

// ---------------- per-node online-softmax GATv2 aggregation ----------------
// ONE WAVE per node: lane ln owns channel pair ch0 = (ln>>4)*32 + (ln&15)*2.
// xb[i][0:128] = xl_i (bf16), xb[i][128:256] = xr_i (bf16). Block 256 thr = 4 nodes.

__global__ __launch_bounds__(256)
void k_edge(const u16* __restrict__ xb, const float* __restrict__ att,
            const float* __restrict__ bias, const int* __restrict__ offs,
            const int* __restrict__ csr, u16* __restrict__ outb,
            float* __restrict__ outf, int relu) {
    int i = blockIdx.x * 4 + (threadIdx.x >> 6);
    if (i >= NN) return;
    int ln = threadIdx.x & 63;
    int ch0 = ((ln >> 4) << 5) + ((ln & 15) << 1);

    unsigned xr2 = *(const unsigned*)&xb[(size_t)i * 256 + 128 + ch0];
    float xri0 = b2f((u16)xr2), xri1 = b2f((u16)(xr2 >> 16));
    float at0 = att[ch0], at1 = att[ch0 + 1];
    int beg = offs[i], end = offs[i + 1];

    float mA = -3.0e38f, sA = 0.f, aA0 = 0.f, aA1 = 0.f;
    float mB = -3.0e38f, sB = 0.f, aB0 = 0.f, aB1 = 0.f;

    for (int p = beg; p < end; p += 2) {
        int ja = csr[p];
        bool hb = (p + 1 < end);
        int jb = hb ? csr[p + 1] : ja;
        unsigned va2 = *(const unsigned*)&xb[(size_t)ja * 256 + ch0];
        unsigned vb2 = *(const unsigned*)&xb[(size_t)jb * 256 + ch0];
        float va0 = b2f((u16)va2), va1 = b2f((u16)(va2 >> 16));
        float vb0 = b2f((u16)vb2), vb1 = b2f((u16)(vb2 >> 16));

        float u0 = va0 + xri0; u0 = (u0 > 0.f) ? u0 : 0.2f * u0;
        float u1 = va1 + xri1; u1 = (u1 > 0.f) ? u1 : 0.2f * u1;
        float ua = u0 * at0 + u1 * at1;
        u0 = vb0 + xri0; u0 = (u0 > 0.f) ? u0 : 0.2f * u0;
        u1 = vb1 + xri1; u1 = (u1 > 0.f) ? u1 : 0.2f * u1;
        float ub = u0 * at0 + u1 * at1;

        ua = red16(ua);
        ub = red16(ub);

        { float mn = fmaxf(mA, ua); float c = __expf(mA - mn), w = __expf(ua - mn);
          sA = sA * c + w; aA0 = aA0 * c + w * va0; aA1 = aA1 * c + w * va1; mA = mn; }
        if (hb) {
          float mn = fmaxf(mB, ub); float c = __expf(mB - mn), w = __expf(ub - mn);
          sB = sB * c + w; aB0 = aB0 * c + w * vb0; aB1 = aB1 * c + w * vb1; mB = mn; }
    }
    float mm = fmaxf(mA, mB);
    float cA = __expf(mA - mm), cB = __expf(mB - mm);
    float s = sA * cA + sB * cB + 1e-16f;
    float inv = 1.f / s;
    float o0 = (aA0 * cA + aB0 * cB) * inv + bias[ch0];
    float o1 = (aA1 * cA + aB1 * cB) * inv + bias[ch0 + 1];
    if (relu) { o0 = fmaxf(o0, 0.f); o1 = fmaxf(o1, 0.f); }
    if (outb) {
        unsigned pk = (unsigned)f2b(o0) | ((unsigned)f2b(o1) << 16);
        *(unsigned*)&outb[(size_t)i * HC + ch0] = pk;
    }
    if (outf) {
        float2 pf = make_float2(o0, o1);
        *(float2*)&outf[(size_t)i * HC + ch0] = pf;
    }
}

// ---------------- tail ----------------

__global__ __launch_bounds__(256)
void k_colsum(const float* __restrict__ h, float* __restrict__ gsum) {
    __shared__ float4 sd[8][32];
    int t = threadIdx.x;
    int c4 = t & 31, rl = t >> 5;
    float sx = 0.f, sy = 0.f, sz = 0.f, sw = 0.f;
    for (int r = blockIdx.x * 8 + rl; r < NN; r += 8 * gridDim.x) {
        float4 v = *(const float4*)&h[(size_t)r * HC + c4 * 4];
        sx += v.x; sy += v.y; sz += v.z; sw += v.w;
    }
    sd[rl][c4] = make_float4(sx, sy, sz, sw);
    __syncthreads();
    if (rl == 0) {
        float4 a = sd[0][c4];
        #pragma unroll
        for (int q = 1; q < 8; ++q) {
            float4 b = sd[q][c4];
            a.x += b.x; a.y += b.y; a.z += b.z; a.w += b.w;
        }
        atomicAdd(&gsum[c4 * 4 + 0], a.x);
        atomicAdd(&gsum[c4 * 4 + 1], a.y);
        atomicAdd(&gsum[c4 * 4 + 2], a.z);
        atomicAdd(&gsum[c4 * 4 + 3], a.w);
    }
}

__global__ void k_clf(const float* __restrict__ gsum, const float* __restrict__ W,
                      const float* __restrict__ bcls, float* __restrict__ out) {
    __shared__ float v[HC];
    int t = threadIdx.x;   // 128
    v[t] = gsum[t] * (1.f / (float)NN);
    __syncthreads();
    if (t < 2) {
        float r = 0.f;
        for (int k = 0; k < HC; ++k) r += v[k] * W[k * 2 + t];
        out[t] = r + bcls[t];
    }
}

// ---------------- launch ----------------

extern "C" void kernel_launch(void* const* d_in, const int* in_sizes, int n_in,
                              void* d_out, int out_size, void* d_ws, size_t ws_size,
                              hipStream_t stream) {
    const float* x = (const float*)d_in[0];
    const int* ei = (const int*)d_in[1];
    const float *Wl[4], *Wr[4], *att[4], *bia[4];
    for (int l = 0; l < 4; ++l) {
        Wl[l] = (const float*)d_in[2 + 4 * l];
        Wr[l] = (const float*)d_in[3 + 4 * l];
        att[l] = (const float*)d_in[4 + 4 * l];
        bia[l] = (const float*)d_in[5 + 4 * l];
    }
    const float* clfW = (const float*)d_in[18];
    const float* clfb = (const float*)d_in[19];
    float* outp = (float*)d_out;

    char* w = (char*)d_ws;
    size_t o = 0;
    auto alloc = [&](size_t bytes) {
        char* p = w + o;
        o = (o + bytes + 255) & ~(size_t)255;
        return p;
    };
    int* cnt   = (int*)alloc((size_t)NN * 4);
    int* offs  = (int*)alloc((size_t)(NN + 1) * 4);
    int* csr   = (int*)alloc((size_t)(EE + NN) * 4);
    int* bsum  = (int*)alloc((size_t)NB1 * 4);
    int* bex   = (int*)alloc(256 * 4);
    u16* WtAll = (u16*)alloc((size_t)WT_TOT * 2);
    u16* xb    = (u16*)alloc((size_t)NN * 256 * 2);
    u16* hb0   = (u16*)alloc((size_t)NN * HC * 2);
    u16* hb1   = (u16*)alloc((size_t)NN * HC * 2);
    float* hfin = (float*)alloc((size_t)NN * HC * 4);
    float* gsum = (float*)alloc(HC * 4);

    // CSR by destination + W cast
    k_zero<<<NB1, 256, 0, stream>>>(cnt, NN);
    k_count<<<(EE + 255) / 256, 256, 0, stream>>>(ei, cnt, gsum);
    k_bsum<<<NB1, 256, 0, stream>>>(cnt, bsum);
    k_bscan<<<1, 256, 0, stream>>>(bsum, bex, offs);
    k_offs<<<NB1, 256, 0, stream>>>(cnt, bex, offs, cnt, csr);
    k_fill<<<(EE + 255) / 256, 256, 0, stream>>>(ei, cnt, csr);
    k_castw_all<<<(WT_TOT + 255) / 256, 256, 0, stream>>>(
        Wl[0], Wr[0], Wl[1], Wr[1], Wl[2], Wr[2], Wl[3], Wr[3], WtAll);

    const int GB = (NN + 63) / 64;   // 782
    const u16* Wt_l[4] = {WtAll, WtAll + WT_L0, WtAll + WT_L0 + WT_LX,
                          WtAll + WT_L0 + 2 * WT_LX};
    const u16* hb_in = nullptr;
    u16* hbb[2] = {hb0, hb1};
    for (int l = 0; l < 4; ++l) {
        if (l == 0) k_gemm<768, true ><<<GB, 256, 0, stream>>>((const void*)x, Wt_l[0], xb);
        else        k_gemm<128, false><<<GB, 256, 0, stream>>>((const void*)hb_in, Wt_l[l], xb);
        u16* ob = (l < 3) ? hbb[l & 1] : nullptr;
        float* of = (l == 3) ? hfin : nullptr;
        k_edge<<<(NN + 3) / 4, 256, 0, stream>>>(xb, att[l], bia[l], offs, csr, ob, of,
                                                 (l < 3) ? 1 : 0);
        hb_in = ob;
    }

    k_colsum<<<504, 256, 0, stream>>>(hfin, gsum);
    k_clf<<<1, 128, 0, stream>>>(gsum, clfW, clfb, outp);
}

// Round 5
// 417.373 us; speedup vs baseline: 2.5696x; 1.1933x over previous
//
#include <hip/hip_runtime.h>
#include <hip/hip_bf16.h>

#define NN 50000
#define EE 640000
#define HC 128
#define NB1 196   // ceil(NN/256)

typedef short bf16x8 __attribute__((ext_vector_type(8)));
typedef float f32x4 __attribute__((ext_vector_type(4)));
typedef unsigned short u16;

__device__ __forceinline__ u16 f2b(float f) {   // RN-even
    unsigned u = __float_as_uint(f);
    unsigned r = u + 0x7FFFu + ((u >> 16) & 1u);
    return (u16)(r >> 16);
}
__device__ __forceinline__ float b2f(u16 h) {
    return __uint_as_float(((unsigned)h) << 16);
}

__device__ __forceinline__ void gload_lds16(const void* g, void* l) {
    __builtin_amdgcn_global_load_lds((const __attribute__((address_space(1))) void*)g,
                                     (__attribute__((address_space(3))) void*)l, 16, 0, 0);
}

// sum across each 16-lane row, all lanes get result: pure DPP (no LDS op)
__device__ __forceinline__ float red16(float x) {
    x += __int_as_float(__builtin_amdgcn_update_dpp(0, __float_as_int(x), 0xB1, 0xF, 0xF, true));
    x += __int_as_float(__builtin_amdgcn_update_dpp(0, __float_as_int(x), 0x4E, 0xF, 0xF, true));
    x += __int_as_float(__builtin_amdgcn_update_dpp(0, __float_as_int(x), 0x141, 0xF, 0xF, true));
    x += __int_as_float(__builtin_amdgcn_update_dpp(0, __float_as_int(x), 0x128, 0xF, 0xF, true));
    return x;
}

// ---------------- CSR build ----------------

__global__ void k_count(const int* __restrict__ ei, int* __restrict__ cnt) {
    int e = blockIdx.x * blockDim.x + threadIdx.x;
    if (e < EE) atomicAdd(&cnt[ei[EE + e]], 1);
}

__global__ void k_bsum(const int* __restrict__ cnt, int* __restrict__ bsum) {
    __shared__ int sd[256];
    int b = blockIdx.x, t = threadIdx.x, i = b * 256 + t;
    sd[t] = (i < NN) ? cnt[i] + 1 : 0;
    __syncthreads();
    for (int o = 128; o; o >>= 1) { if (t < o) sd[t] += sd[t + o]; __syncthreads(); }
    if (!t) bsum[b] = sd[0];
}

__global__ void k_bscan(const int* __restrict__ bsum, int* __restrict__ bex,
                        int* __restrict__ offs) {
    __shared__ int sd[256];
    int t = threadIdx.x;
    int v = (t < NB1) ? bsum[t] : 0;
    sd[t] = v; __syncthreads();
    for (int o = 1; o < 256; o <<= 1) {
        int u = (t >= o) ? sd[t - o] : 0;
        __syncthreads(); sd[t] += u; __syncthreads();
    }
    bex[t] = sd[t] - v;
    if (t == NB1 - 1) offs[NN] = sd[t];
}

// offs + self-loop + cursor init fused (cursor aliases cnt)
__global__ void k_offs(const int* __restrict__ cnt_in, const int* __restrict__ bex,
                       int* __restrict__ offs, int* __restrict__ cursor,
                       int* __restrict__ csr) {
    __shared__ int sd[256];
    int b = blockIdx.x, t = threadIdx.x, i = b * 256 + t;
    int v = (i < NN) ? cnt_in[i] + 1 : 0;
    sd[t] = v; __syncthreads();
    for (int o = 1; o < 256; o <<= 1) {
        int u = (t >= o) ? sd[t - o] : 0;
        __syncthreads(); sd[t] += u; __syncthreads();
    }
    if (i < NN) {
        int o = bex[b] + sd[t] - v;
        offs[i] = o;
        csr[o] = i;          // self loop first
        cursor[i] = o + 1;
    }
}

__global__ void k_fill(const int* __restrict__ ei, int* __restrict__ cursor,
                       int* __restrict__ csr) {
    int e = blockIdx.x * blockDim.x + threadIdx.x;
    if (e < EE) {
        int s = ei[e], d = ei[EE + e];
        int pos = atomicAdd(&cursor[d], 1);
        csr[pos] = s;
    }
}

// ---------------- all-layer W cast+transpose ----------------

#define WT_L0 196608              // 256*768
#define WT_LX 32768               // 256*128
#define WT_TOT (WT_L0 + 3 * WT_LX)

__global__ void k_castw_all(const float* __restrict__ Wl1, const float* __restrict__ Wr1,
                            const float* __restrict__ Wl2, const float* __restrict__ Wr2,
                            const float* __restrict__ Wl3, const float* __restrict__ Wr3,
                            const float* __restrict__ Wl4, const float* __restrict__ Wr4,
                            u16* __restrict__ WtAll) {
    int gid = blockIdx.x * 256 + threadIdx.x;
    if (gid >= WT_TOT) return;
    const float *Wl, *Wr;
    int idx, K, base;
    if (gid < WT_L0) { Wl = Wl1; Wr = Wr1; idx = gid; K = 768; base = 0; }
    else {
        int r = gid - WT_L0;
        int l = r >> 15; idx = r & (WT_LX - 1); K = 128; base = WT_L0 + l * WT_LX;
        if (l == 0)      { Wl = Wl2; Wr = Wr2; }
        else if (l == 1) { Wl = Wl3; Wr = Wr3; }
        else             { Wl = Wl4; Wr = Wr4; }
    }
    int c = idx / K, k = idx - c * K;
    float v = (c < 128) ? Wl[k * 128 + c] : Wr[k * 128 + (c - 128)];
    WtAll[base + idx] = f2b(v);
}

// ---------------- MFMA bf16 GEMM ----------------
// xb[N][256] = A[N,K] @ Wt^T (bf16 out). Tile 64 rows x 256 cols, 4 waves (64x64 each), BK=64.

template<int K, bool F32A>
__global__ __launch_bounds__(256)
void k_gemm(const void* __restrict__ Ag, const u16* __restrict__ Wt,
            u16* __restrict__ xb) {
    __shared__ __align__(16) u16 As[64 * 64];
    __shared__ __align__(16) u16 Bs[256 * 64];
    const int tid = threadIdx.x;
    const int wv = tid >> 6, ln = tid & 63;
    const int m0 = blockIdx.x * 64;
    const int lrow = ln & 15, g = ln >> 4;

    f32x4 acc[4][4] = {};

    const float* Af = (const float*)Ag;
    const u16* Ab = (const u16*)Ag;
    const int arow = tid >> 2, aq = tid & 3;
    int arg = m0 + arow; if (arg >= NN) arg = 0;
    float4 ra0, ra1, ra2, ra3;

    if constexpr (F32A) {
        const float* src = Af + (size_t)arg * K + aq * 16;
        ra0 = *(const float4*)(src);
        ra1 = *(const float4*)(src + 4);
        ra2 = *(const float4*)(src + 8);
        ra3 = *(const float4*)(src + 12);
    }

    constexpr int NSTEP = K / 64;
    for (int ks = 0; ks < NSTEP; ++ks) {
        if constexpr (F32A) {
            const int s = arow & 7;
            bf16x8 v0, v1;
            v0[0] = (short)f2b(ra0.x); v0[1] = (short)f2b(ra0.y);
            v0[2] = (short)f2b(ra0.z); v0[3] = (short)f2b(ra0.w);
            v0[4] = (short)f2b(ra1.x); v0[5] = (short)f2b(ra1.y);
            v0[6] = (short)f2b(ra1.z); v0[7] = (short)f2b(ra1.w);
            v1[0] = (short)f2b(ra2.x); v1[1] = (short)f2b(ra2.y);
            v1[2] = (short)f2b(ra2.z); v1[3] = (short)f2b(ra2.w);
            v1[4] = (short)f2b(ra3.x); v1[5] = (short)f2b(ra3.y);
            v1[6] = (short)f2b(ra3.z); v1[7] = (short)f2b(ra3.w);
            *(bf16x8*)&As[arow * 64 + (((aq * 2) ^ s) * 8)] = v0;
            *(bf16x8*)&As[arow * 64 + (((aq * 2 + 1) ^ s) * 8)] = v1;
        } else {
            #pragma unroll
            for (int q = 0; q < 2; ++q) {
                int r8 = (wv * 2 + q) * 8;
                int row = r8 + (ln >> 3);
                int lc = (ln & 7) ^ (row & 7);
                int rg = m0 + row; if (rg >= NN) rg = 0;
                gload_lds16(Ab + (size_t)rg * K + ks * 64 + lc * 8, &As[r8 * 64]);
            }
        }
        #pragma unroll
        for (int q = 0; q < 8; ++q) {
            int r8 = (wv * 8 + q) * 8;
            int row = r8 + (ln >> 3);
            int lc = (ln & 7) ^ (row & 7);
            gload_lds16(Wt + (size_t)row * K + ks * 64 + lc * 8, &Bs[r8 * 64]);
        }
        __syncthreads();   // drains vmcnt (gload_lds) + lgkmcnt (ds_write)

        if constexpr (F32A) {
            if (ks + 1 < NSTEP) {   // T14: issue next tile's loads, consume after next barrier
                const float* src = Af + (size_t)arg * K + (ks + 1) * 64 + aq * 16;
                ra0 = *(const float4*)(src);
                ra1 = *(const float4*)(src + 4);
                ra2 = *(const float4*)(src + 8);
                ra3 = *(const float4*)(src + 12);
            }
        }

        #pragma unroll
        for (int kk = 0; kk < 2; ++kk) {
            bf16x8 af[4], bfr[4];
            #pragma unroll
            for (int f = 0; f < 4; ++f) {
                int r = f * 16 + lrow;
                af[f] = *(const bf16x8*)&As[r * 64 + (((kk * 4 + g) ^ (r & 7)) * 8)];
                int c = wv * 64 + f * 16 + lrow;
                bfr[f] = *(const bf16x8*)&Bs[c * 64 + (((kk * 4 + g) ^ (c & 7)) * 8)];
            }
            #pragma unroll
            for (int i = 0; i < 4; ++i)
                #pragma unroll
                for (int j = 0; j < 4; ++j)
                    acc[i][j] = __builtin_amdgcn_mfma_f32_16x16x32_bf16(af[i], bfr[j], acc[i][j], 0, 0, 0);
        }
        __syncthreads();
    }

    const int crow0 = m0 + (g << 2);
    const int ccol0 = wv * 64 + lrow;
    #pragma unroll
    for (int i = 0; i < 4; ++i)
        #pragma unroll
        for (int rr = 0; rr < 4; ++rr) {
            int row = crow0 + i * 16 + rr;
            if (row < NN) {
                #pragma unroll
                for (int j = 0; j < 4; ++j)
                    xb[(size_t)row * 256 + ccol0 + j * 16] = f2b(acc[i][j][rr]);
            }
        }
}

// ---------------- per-node online-softmax GATv2 aggregation ----------------
// ONE WAVE per node; lane ln owns channel pair ch0 = (ln>>4)*32 + (ln&15)*2.
// Neighbor indices loaded 64-at-a-time coalesced into lanes, broadcast by __shfl;
// 4 independent gather/softmax streams (named scalars, no runtime-indexed arrays).

__global__ __launch_bounds__(256)
void k_edge(const u16* __restrict__ xb, const float* __restrict__ att,
            const float* __restrict__ bias, const int* __restrict__ offs,
            const int* __restrict__ csr, u16* __restrict__ outb,
            float* __restrict__ outf, int relu) {
    int i = blockIdx.x * 4 + (threadIdx.x >> 6);
    if (i >= NN) return;
    int ln = threadIdx.x & 63;
    int ch0 = ((ln >> 4) << 5) + ((ln & 15) << 1);

    unsigned xr2 = *(const unsigned*)&xb[(size_t)i * 256 + 128 + ch0];
    float xri0 = b2f((u16)xr2), xri1 = b2f((u16)(xr2 >> 16));
    float2 atv = *(const float2*)&att[ch0];
    const float at0 = atv.x, at1 = atv.y;
    int beg = offs[i];
    int deg = offs[i + 1] - beg;

    float m0v = -3.0e38f, s0v = 0.f, p00 = 0.f, p01 = 0.f;
    float m1v = -3.0e38f, s1v = 0.f, p10 = 0.f, p11 = 0.f;
    float m2v = -3.0e38f, s2v = 0.f, p20 = 0.f, p21 = 0.f;
    float m3v = -3.0e38f, s3v = 0.f, p30 = 0.f, p31 = 0.f;

#define GATH(k, jj) unsigned w##k = *(const unsigned*)&xb[(size_t)(jj) * 256 + ch0];
#define UPD(k, M, S, A0, A1) { \
    float v0 = b2f((u16)w##k), v1 = b2f((u16)(w##k >> 16)); \
    float u0 = v0 + xri0; u0 = (u0 > 0.f) ? u0 : 0.2f * u0; \
    float u1 = v1 + xri1; u1 = (u1 > 0.f) ? u1 : 0.2f * u1; \
    float e = red16(u0 * at0 + u1 * at1); \
    float mn = fmaxf(M, e); float c = __expf(M - mn), ww = __expf(e - mn); \
    S = S * c + ww; A0 = A0 * c + ww * v0; A1 = A1 * c + ww * v1; M = mn; }

    for (int base = 0; base < deg; base += 64) {
        int lim = deg - base; if (lim > 64) lim = 64;
        int idxv = (base + ln < deg) ? csr[beg + base + ln] : 0;
        int p = 0;
        for (; p + 4 <= lim; p += 4) {
            int j0 = __shfl(idxv, p);
            int j1 = __shfl(idxv, p + 1);
            int j2 = __shfl(idxv, p + 2);
            int j3 = __shfl(idxv, p + 3);
            GATH(0, j0) GATH(1, j1) GATH(2, j2) GATH(3, j3)
            UPD(0, m0v, s0v, p00, p01)
            UPD(1, m1v, s1v, p10, p11)
            UPD(2, m2v, s2v, p20, p21)
            UPD(3, m3v, s3v, p30, p31)
        }
        for (; p < lim; ++p) {
            int j0 = __shfl(idxv, p);
            GATH(4, j0)
            UPD(4, m0v, s0v, p00, p01)
        }
    }
#undef GATH
#undef UPD

    float mm = fmaxf(fmaxf(m0v, m1v), fmaxf(m2v, m3v));
    float c0 = __expf(m0v - mm), c1 = __expf(m1v - mm);
    float c2 = __expf(m2v - mm), c3 = __expf(m3v - mm);
    float s = s0v * c0 + s1v * c1 + s2v * c2 + s3v * c3 + 1e-16f;
    float inv = 1.f / s;
    float2 bv = *(const float2*)&bias[ch0];
    float o0 = (p00 * c0 + p10 * c1 + p20 * c2 + p30 * c3) * inv + bv.x;
    float o1 = (p01 * c0 + p11 * c1 + p21 * c2 + p31 * c3) * inv + bv.y;
    if (relu) { o0 = fmaxf(o0, 0.f); o1 = fmaxf(o1, 0.f); }
    if (outb) {
        unsigned pk = (unsigned)f2b(o0) | ((unsigned)f2b(o1) << 16);
        *(unsigned*)&outb[(size_t)i * HC + ch0] = pk;
    }
    if (outf) {
        *(float2*)&outf[(size_t)i * HC + ch0] = make_float2(o0, o1);
    }
}

// ---------------- tail ----------------

__global__ __launch_bounds__(256)
void k_colsum(const float* __restrict__ h, float* __restrict__ gsum) {
    __shared__ float4 sd[8][32];
    int t = threadIdx.x;
    int c4 = t & 31, rl = t >> 5;
    float sx = 0.f, sy = 0.f, sz = 0.f, sw = 0.f;
    for (int r = blockIdx.x * 8 + rl; r < NN; r += 8 * gridDim.x) {
        float4 v = *(const float4*)&h[(size_t)r * HC + c4 * 4];
        sx += v.x; sy += v.y; sz += v.z; sw += v.w;
    }
    sd[rl][c4] = make_float4(sx, sy, sz, sw);
    __syncthreads();
    if (rl == 0) {
        float4 a = sd[0][c4];
        #pragma unroll
        for (int q = 1; q < 8; ++q) {
            float4 b = sd[q][c4];
            a.x += b.x; a.y += b.y; a.z += b.z; a.w += b.w;
        }
        atomicAdd(&gsum[c4 * 4 + 0], a.x);
        atomicAdd(&gsum[c4 * 4 + 1], a.y);
        atomicAdd(&gsum[c4 * 4 + 2], a.z);
        atomicAdd(&gsum[c4 * 4 + 3], a.w);
    }
}

__global__ void k_clf(const float* __restrict__ gsum, const float* __restrict__ W,
                      const float* __restrict__ bcls, float* __restrict__ out) {
    __shared__ float v[HC];
    int t = threadIdx.x;   // 128
    v[t] = gsum[t] * (1.f / (float)NN);
    __syncthreads();
    if (t < 2) {
        float r = 0.f;
        for (int k = 0; k < HC; ++k) r += v[k] * W[k * 2 + t];
        out[t] = r + bcls[t];
    }
}

// ---------------- launch ----------------

extern "C" void kernel_launch(void* const* d_in, const int* in_sizes, int n_in,
                              void* d_out, int out_size, void* d_ws, size_t ws_size,
                              hipStream_t stream) {
    const float* x = (const float*)d_in[0];
    const int* ei = (const int*)d_in[1];
    const float *Wl[4], *Wr[4], *att[4], *bia[4];
    for (int l = 0; l < 4; ++l) {
        Wl[l] = (const float*)d_in[2 + 4 * l];
        Wr[l] = (const float*)d_in[3 + 4 * l];
        att[l] = (const float*)d_in[4 + 4 * l];
        bia[l] = (const float*)d_in[5 + 4 * l];
    }
    const float* clfW = (const float*)d_in[18];
    const float* clfb = (const float*)d_in[19];
    float* outp = (float*)d_out;

    char* w = (char*)d_ws;
    size_t o = 0;
    auto alloc = [&](size_t bytes) {
        char* p = w + o;
        o = (o + bytes + 255) & ~(size_t)255;
        return p;
    };
    int* cnt    = (int*)alloc((size_t)NN * 4);     // also cursor
    float* gsum = (float*)alloc(HC * 4);           // adjacent to cnt: one memset covers both
    size_t zspan = o;                              // bytes from cnt to end of gsum (padded)
    int* offs  = (int*)alloc((size_t)(NN + 1) * 4);
    int* csr   = (int*)alloc((size_t)(EE + NN) * 4);
    int* bsum  = (int*)alloc((size_t)NB1 * 4);
    int* bex   = (int*)alloc(256 * 4);
    u16* WtAll = (u16*)alloc((size_t)WT_TOT * 2);
    u16* xb    = (u16*)alloc((size_t)NN * 256 * 2);
    u16* hb0   = (u16*)alloc((size_t)NN * HC * 2);
    u16* hb1   = (u16*)alloc((size_t)NN * HC * 2);
    float* hfin = (float*)alloc((size_t)NN * HC * 4);

    // CSR by destination + W cast
    hipMemsetAsync(cnt, 0, zspan, stream);
    k_count<<<(EE + 255) / 256, 256, 0, stream>>>(ei, cnt);
    k_bsum<<<NB1, 256, 0, stream>>>(cnt, bsum);
    k_bscan<<<1, 256, 0, stream>>>(bsum, bex, offs);
    k_offs<<<NB1, 256, 0, stream>>>(cnt, bex, offs, cnt, csr);
    k_fill<<<(EE + 255) / 256, 256, 0, stream>>>(ei, cnt, csr);
    k_castw_all<<<(WT_TOT + 255) / 256, 256, 0, stream>>>(
        Wl[0], Wr[0], Wl[1], Wr[1], Wl[2], Wr[2], Wl[3], Wr[3], WtAll);

    const int GB = (NN + 63) / 64;   // 782
    const u16* Wt_l[4] = {WtAll, WtAll + WT_L0, WtAll + WT_L0 + WT_LX,
                          WtAll + WT_L0 + 2 * WT_LX};
    const u16* hb_in = nullptr;
    u16* hbb[2] = {hb0, hb1};
    for (int l = 0; l < 4; ++l) {
        if (l == 0) k_gemm<768, true ><<<GB, 256, 0, stream>>>((const void*)x, Wt_l[0], xb);
        else        k_gemm<128, false><<<GB, 256, 0, stream>>>((const void*)hb_in, Wt_l[l], xb);
        u16* ob = (l < 3) ? hbb[l & 1] : nullptr;
        float* of = (l == 3) ? hfin : nullptr;
        k_edge<<<(NN + 3) / 4, 256, 0, stream>>>(xb, att[l], bia[l], offs, csr, ob, of,
                                                 (l < 3) ? 1 : 0);
        hb_in = ob;
    }

    k_colsum<<<504, 256, 0, stream>>>(hfin, gsum);
    k_clf<<<1, 128, 0, stream>>>(gsum, clfW, clfb, outp);
}

// Round 6
// 394.502 us; speedup vs baseline: 2.7186x; 1.0580x over previous
//
#include <hip/hip_runtime.h>
#include <hip/hip_bf16.h>

#define NN 50000
#define EE 640000
#define HC 128
#define NB1 196   // ceil(NN/256)

typedef short bf16x8 __attribute__((ext_vector_type(8)));
typedef float f32x4 __attribute__((ext_vector_type(4)));
typedef unsigned short u16;

__device__ __forceinline__ u16 f2b(float f) {   // RN-even
    unsigned u = __float_as_uint(f);
    unsigned r = u + 0x7FFFu + ((u >> 16) & 1u);
    return (u16)(r >> 16);
}
__device__ __forceinline__ float b2f(u16 h) {
    return __uint_as_float(((unsigned)h) << 16);
}

__device__ __forceinline__ void gload_lds16(const void* g, void* l) {
    __builtin_amdgcn_global_load_lds((const __attribute__((address_space(1))) void*)g,
                                     (__attribute__((address_space(3))) void*)l, 16, 0, 0);
}

// sum across each 16-lane row, all lanes get result: pure DPP (no LDS op)
__device__ __forceinline__ float red16(float x) {
    x += __int_as_float(__builtin_amdgcn_update_dpp(0, __float_as_int(x), 0xB1, 0xF, 0xF, true));
    x += __int_as_float(__builtin_amdgcn_update_dpp(0, __float_as_int(x), 0x4E, 0xF, 0xF, true));
    x += __int_as_float(__builtin_amdgcn_update_dpp(0, __float_as_int(x), 0x141, 0xF, 0xF, true));
    x += __int_as_float(__builtin_amdgcn_update_dpp(0, __float_as_int(x), 0x128, 0xF, 0xF, true));
    return x;
}

// ---------------- CSR build ----------------

__global__ void k_count(const int* __restrict__ ei, int* __restrict__ cnt) {
    int e = blockIdx.x * blockDim.x + threadIdx.x;
    if (e < EE) atomicAdd(&cnt[ei[EE + e]], 1);
}

__global__ void k_bsum(const int* __restrict__ cnt, int* __restrict__ bsum) {
    __shared__ int sd[256];
    int b = blockIdx.x, t = threadIdx.x, i = b * 256 + t;
    sd[t] = (i < NN) ? cnt[i] + 1 : 0;
    __syncthreads();
    for (int o = 128; o; o >>= 1) { if (t < o) sd[t] += sd[t + o]; __syncthreads(); }
    if (!t) bsum[b] = sd[0];
}

__global__ void k_bscan(const int* __restrict__ bsum, int* __restrict__ bex,
                        int* __restrict__ offs) {
    __shared__ int sd[256];
    int t = threadIdx.x;
    int v = (t < NB1) ? bsum[t] : 0;
    sd[t] = v; __syncthreads();
    for (int o = 1; o < 256; o <<= 1) {
        int u = (t >= o) ? sd[t - o] : 0;
        __syncthreads(); sd[t] += u; __syncthreads();
    }
    bex[t] = sd[t] - v;
    if (t == NB1 - 1) offs[NN] = sd[t];
}

// offs + self-loop + cursor init fused (cursor aliases cnt)
__global__ void k_offs(const int* __restrict__ cnt_in, const int* __restrict__ bex,
                       int* __restrict__ offs, int* __restrict__ cursor,
                       int* __restrict__ csr) {
    __shared__ int sd[256];
    int b = blockIdx.x, t = threadIdx.x, i = b * 256 + t;
    int v = (i < NN) ? cnt_in[i] + 1 : 0;
    sd[t] = v; __syncthreads();
    for (int o = 1; o < 256; o <<= 1) {
        int u = (t >= o) ? sd[t - o] : 0;
        __syncthreads(); sd[t] += u; __syncthreads();
    }
    if (i < NN) {
        int o = bex[b] + sd[t] - v;
        offs[i] = o;
        csr[o] = i;          // self loop first
        cursor[i] = o + 1;
    }
}

__global__ void k_fill(const int* __restrict__ ei, int* __restrict__ cursor,
                       int* __restrict__ csr) {
    int e = blockIdx.x * blockDim.x + threadIdx.x;
    if (e < EE) {
        int s = ei[e], d = ei[EE + e];
        int pos = atomicAdd(&cursor[d], 1);
        csr[pos] = s;
    }
}

// ---------------- all-layer W cast+transpose ----------------

#define WT_L0 196608              // 256*768
#define WT_LX 32768               // 256*128
#define WT_TOT (WT_L0 + 3 * WT_LX)

__global__ void k_castw_all(const float* __restrict__ Wl1, const float* __restrict__ Wr1,
                            const float* __restrict__ Wl2, const float* __restrict__ Wr2,
                            const float* __restrict__ Wl3, const float* __restrict__ Wr3,
                            const float* __restrict__ Wl4, const float* __restrict__ Wr4,
                            u16* __restrict__ WtAll) {
    int gid = blockIdx.x * 256 + threadIdx.x;
    if (gid >= WT_TOT) return;
    const float *Wl, *Wr;
    int idx, K, base;
    if (gid < WT_L0) { Wl = Wl1; Wr = Wr1; idx = gid; K = 768; base = 0; }
    else {
        int r = gid - WT_L0;
        int l = r >> 15; idx = r & (WT_LX - 1); K = 128; base = WT_L0 + l * WT_LX;
        if (l == 0)      { Wl = Wl2; Wr = Wr2; }
        else if (l == 1) { Wl = Wl3; Wr = Wr3; }
        else             { Wl = Wl4; Wr = Wr4; }
    }
    int c = idx / K, k = idx - c * K;
    float v = (c < 128) ? Wl[k * 128 + c] : Wr[k * 128 + (c - 128)];
    WtAll[base + idx] = f2b(v);
}

// ---------------- MFMA bf16 GEMM ----------------
// xb[N][256] = A[N,K] @ Wt^T (bf16 out). Tile 128 rows x 256 cols, 8 waves (2x4, 64x64 each),
// BK=64, 512 threads. LDS: As[128][64] u16 (16KB), Bs[256][64] u16 (32KB) = 48KB.
// 16B-chunk XOR swizzle phys = logical ^ (row&7), pre-swizzled global source (linear LDS dest).

template<int K, bool F32A>
__global__ __launch_bounds__(512, 4)
void k_gemm(const void* __restrict__ Ag, const u16* __restrict__ Wt,
            u16* __restrict__ xb) {
    __shared__ __align__(16) u16 As[128 * 64];
    __shared__ __align__(16) u16 Bs[256 * 64];
    const int tid = threadIdx.x;
    const int wv = tid >> 6, ln = tid & 63;
    const int wr = wv >> 2, wc = wv & 3;
    const int m0 = blockIdx.x * 128;
    const int lrow = ln & 15, g = ln >> 4;

    f32x4 acc[4][4] = {};

    const float* Af = (const float*)Ag;
    const u16* Ab = (const u16*)Ag;
    const int arow = tid >> 2, aq = tid & 3;   // 512 thr -> arow 0..127
    int arg = m0 + arow; if (arg >= NN) arg = 0;
    float4 ra0, ra1, ra2, ra3;

    if constexpr (F32A) {
        const float* src = Af + (size_t)arg * K + aq * 16;
        ra0 = *(const float4*)(src);
        ra1 = *(const float4*)(src + 4);
        ra2 = *(const float4*)(src + 8);
        ra3 = *(const float4*)(src + 12);
    }

    constexpr int NSTEP = K / 64;
    for (int ks = 0; ks < NSTEP; ++ks) {
        if constexpr (F32A) {
            const int s = arow & 7;
            bf16x8 v0, v1;
            v0[0] = (short)f2b(ra0.x); v0[1] = (short)f2b(ra0.y);
            v0[2] = (short)f2b(ra0.z); v0[3] = (short)f2b(ra0.w);
            v0[4] = (short)f2b(ra1.x); v0[5] = (short)f2b(ra1.y);
            v0[6] = (short)f2b(ra1.z); v0[7] = (short)f2b(ra1.w);
            v1[0] = (short)f2b(ra2.x); v1[1] = (short)f2b(ra2.y);
            v1[2] = (short)f2b(ra2.z); v1[3] = (short)f2b(ra2.w);
            v1[4] = (short)f2b(ra3.x); v1[5] = (short)f2b(ra3.y);
            v1[6] = (short)f2b(ra3.z); v1[7] = (short)f2b(ra3.w);
            *(bf16x8*)&As[arow * 64 + (((aq * 2) ^ s) * 8)] = v0;
            *(bf16x8*)&As[arow * 64 + (((aq * 2 + 1) ^ s) * 8)] = v1;
        } else {
            #pragma unroll
            for (int q = 0; q < 2; ++q) {
                int r8 = (wv * 2 + q) * 8;          // 16 segs x 8 rows = 128
                int row = r8 + (ln >> 3);
                int lc = (ln & 7) ^ (row & 7);
                int rg = m0 + row; if (rg >= NN) rg = 0;
                gload_lds16(Ab + (size_t)rg * K + ks * 64 + lc * 8, &As[r8 * 64]);
            }
        }
        #pragma unroll
        for (int q = 0; q < 4; ++q) {
            int r8 = (wv * 4 + q) * 8;              // 32 segs x 8 rows = 256
            int row = r8 + (ln >> 3);
            int lc = (ln & 7) ^ (row & 7);
            gload_lds16(Wt + (size_t)row * K + ks * 64 + lc * 8, &Bs[r8 * 64]);
        }
        __syncthreads();   // drains vmcnt (gload_lds) + lgkmcnt (ds_write)

        if constexpr (F32A) {
            if (ks + 1 < NSTEP) {   // T14: issue next tile's loads, consume after next barrier
                const float* src = Af + (size_t)arg * K + (ks + 1) * 64 + aq * 16;
                ra0 = *(const float4*)(src);
                ra1 = *(const float4*)(src + 4);
                ra2 = *(const float4*)(src + 8);
                ra3 = *(const float4*)(src + 12);
            }
        }

        #pragma unroll
        for (int kk = 0; kk < 2; ++kk) {
            bf16x8 af[4], bfr[4];
            #pragma unroll
            for (int f = 0; f < 4; ++f) {
                int r = wr * 64 + f * 16 + lrow;
                af[f] = *(const bf16x8*)&As[r * 64 + (((kk * 4 + g) ^ (r & 7)) * 8)];
                int c = wc * 64 + f * 16 + lrow;
                bfr[f] = *(const bf16x8*)&Bs[c * 64 + (((kk * 4 + g) ^ (c & 7)) * 8)];
            }
            #pragma unroll
            for (int i = 0; i < 4; ++i)
                #pragma unroll
                for (int j = 0; j < 4; ++j)
                    acc[i][j] = __builtin_amdgcn_mfma_f32_16x16x32_bf16(af[i], bfr[j], acc[i][j], 0, 0, 0);
        }
        __syncthreads();
    }

    const int crow0 = m0 + wr * 64 + (g << 2);
    const int ccol0 = wc * 64 + lrow;
    #pragma unroll
    for (int i = 0; i < 4; ++i)
        #pragma unroll
        for (int rr = 0; rr < 4; ++rr) {
            int row = crow0 + i * 16 + rr;
            if (row < NN) {
                #pragma unroll
                for (int j = 0; j < 4; ++j)
                    xb[(size_t)row * 256 + ccol0 + j * 16] = f2b(acc[i][j][rr]);
            }
        }
}

// ---------------- per-node online-softmax GATv2 aggregation ----------------
// ONE WAVE per node; lane ln owns channel pair ch0 = (ln>>4)*32 + (ln&15)*2.
// Neighbor indices loaded 64-at-a-time coalesced into lanes, broadcast by __shfl;
// 4 independent gather/softmax streams (named scalars, no runtime-indexed arrays).

__global__ __launch_bounds__(256)
void k_edge(const u16* __restrict__ xb, const float* __restrict__ att,
            const float* __restrict__ bias, const int* __restrict__ offs,
            const int* __restrict__ csr, u16* __restrict__ outb,
            float* __restrict__ outf, int relu) {
    int i = blockIdx.x * 4 + (threadIdx.x >> 6);
    if (i >= NN) return;
    int ln = threadIdx.x & 63;
    int ch0 = ((ln >> 4) << 5) + ((ln & 15) << 1);

    unsigned xr2 = *(const unsigned*)&xb[(size_t)i * 256 + 128 + ch0];
    float xri0 = b2f((u16)xr2), xri1 = b2f((u16)(xr2 >> 16));
    float2 atv = *(const float2*)&att[ch0];
    const float at0 = atv.x, at1 = atv.y;
    int beg = offs[i];
    int deg = offs[i + 1] - beg;

    float m0v = -3.0e38f, s0v = 0.f, p00 = 0.f, p01 = 0.f;
    float m1v = -3.0e38f, s1v = 0.f, p10 = 0.f, p11 = 0.f;
    float m2v = -3.0e38f, s2v = 0.f, p20 = 0.f, p21 = 0.f;
    float m3v = -3.0e38f, s3v = 0.f, p30 = 0.f, p31 = 0.f;

#define GATH(k, jj) unsigned w##k = *(const unsigned*)&xb[(size_t)(jj) * 256 + ch0];
#define UPD(k, M, S, A0, A1) { \
    float v0 = b2f((u16)w##k), v1 = b2f((u16)(w##k >> 16)); \
    float u0 = v0 + xri0; u0 = (u0 > 0.f) ? u0 : 0.2f * u0; \
    float u1 = v1 + xri1; u1 = (u1 > 0.f) ? u1 : 0.2f * u1; \
    float e = red16(u0 * at0 + u1 * at1); \
    float mn = fmaxf(M, e); float c = __expf(M - mn), ww = __expf(e - mn); \
    S = S * c + ww; A0 = A0 * c + ww * v0; A1 = A1 * c + ww * v1; M = mn; }

    for (int base = 0; base < deg; base += 64) {
        int lim = deg - base; if (lim > 64) lim = 64;
        int idxv = (base + ln < deg) ? csr[beg + base + ln] : 0;
        int p = 0;
        for (; p + 4 <= lim; p += 4) {
            int j0 = __shfl(idxv, p);
            int j1 = __shfl(idxv, p + 1);
            int j2 = __shfl(idxv, p + 2);
            int j3 = __shfl(idxv, p + 3);
            GATH(0, j0) GATH(1, j1) GATH(2, j2) GATH(3, j3)
            UPD(0, m0v, s0v, p00, p01)
            UPD(1, m1v, s1v, p10, p11)
            UPD(2, m2v, s2v, p20, p21)
            UPD(3, m3v, s3v, p30, p31)
        }
        for (; p < lim; ++p) {
            int j0 = __shfl(idxv, p);
            GATH(4, j0)
            UPD(4, m0v, s0v, p00, p01)
        }
    }
#undef GATH
#undef UPD

    float mm = fmaxf(fmaxf(m0v, m1v), fmaxf(m2v, m3v));
    float c0 = __expf(m0v - mm), c1 = __expf(m1v - mm);
    float c2 = __expf(m2v - mm), c3 = __expf(m3v - mm);
    float s = s0v * c0 + s1v * c1 + s2v * c2 + s3v * c3 + 1e-16f;
    float inv = 1.f / s;
    float2 bv = *(const float2*)&bias[ch0];
    float o0 = (p00 * c0 + p10 * c1 + p20 * c2 + p30 * c3) * inv + bv.x;
    float o1 = (p01 * c0 + p11 * c1 + p21 * c2 + p31 * c3) * inv + bv.y;
    if (relu) { o0 = fmaxf(o0, 0.f); o1 = fmaxf(o1, 0.f); }
    if (outb) {
        unsigned pk = (unsigned)f2b(o0) | ((unsigned)f2b(o1) << 16);
        *(unsigned*)&outb[(size_t)i * HC + ch0] = pk;
    }
    if (outf) {
        *(float2*)&outf[(size_t)i * HC + ch0] = make_float2(o0, o1);
    }
}

// ---------------- tail ----------------

__global__ __launch_bounds__(256)
void k_colsum(const float* __restrict__ h, float* __restrict__ gsum) {
    __shared__ float4 sd[8][32];
    int t = threadIdx.x;
    int c4 = t & 31, rl = t >> 5;
    float sx = 0.f, sy = 0.f, sz = 0.f, sw = 0.f;
    for (int r = blockIdx.x * 8 + rl; r < NN; r += 8 * gridDim.x) {
        float4 v = *(const float4*)&h[(size_t)r * HC + c4 * 4];
        sx += v.x; sy += v.y; sz += v.z; sw += v.w;
    }
    sd[rl][c4] = make_float4(sx, sy, sz, sw);
    __syncthreads();
    if (rl == 0) {
        float4 a = sd[0][c4];
        #pragma unroll
        for (int q = 1; q < 8; ++q) {
            float4 b = sd[q][c4];
            a.x += b.x; a.y += b.y; a.z += b.z; a.w += b.w;
        }
        atomicAdd(&gsum[c4 * 4 + 0], a.x);
        atomicAdd(&gsum[c4 * 4 + 1], a.y);
        atomicAdd(&gsum[c4 * 4 + 2], a.z);
        atomicAdd(&gsum[c4 * 4 + 3], a.w);
    }
}

__global__ void k_clf(const float* __restrict__ gsum, const float* __restrict__ W,
                      const float* __restrict__ bcls, float* __restrict__ out) {
    __shared__ float v[HC];
    int t = threadIdx.x;   // 128
    v[t] = gsum[t] * (1.f / (float)NN);
    __syncthreads();
    if (t < 2) {
        float r = 0.f;
        for (int k = 0; k < HC; ++k) r += v[k] * W[k * 2 + t];
        out[t] = r + bcls[t];
    }
}

// ---------------- launch ----------------

extern "C" void kernel_launch(void* const* d_in, const int* in_sizes, int n_in,
                              void* d_out, int out_size, void* d_ws, size_t ws_size,
                              hipStream_t stream) {
    const float* x = (const float*)d_in[0];
    const int* ei = (const int*)d_in[1];
    const float *Wl[4], *Wr[4], *att[4], *bia[4];
    for (int l = 0; l < 4; ++l) {
        Wl[l] = (const float*)d_in[2 + 4 * l];
        Wr[l] = (const float*)d_in[3 + 4 * l];
        att[l] = (const float*)d_in[4 + 4 * l];
        bia[l] = (const float*)d_in[5 + 4 * l];
    }
    const float* clfW = (const float*)d_in[18];
    const float* clfb = (const float*)d_in[19];
    float* outp = (float*)d_out;

    char* w = (char*)d_ws;
    size_t o = 0;
    auto alloc = [&](size_t bytes) {
        char* p = w + o;
        o = (o + bytes + 255) & ~(size_t)255;
        return p;
    };
    int* cnt    = (int*)alloc((size_t)NN * 4);     // also cursor
    float* gsum = (float*)alloc(HC * 4);           // adjacent to cnt: one memset covers both
    size_t zspan = o;                              // bytes from cnt to end of gsum (padded)
    int* offs  = (int*)alloc((size_t)(NN + 1) * 4);
    int* csr   = (int*)alloc((size_t)(EE + NN) * 4);
    int* bsum  = (int*)alloc((size_t)NB1 * 4);
    int* bex   = (int*)alloc(256 * 4);
    u16* WtAll = (u16*)alloc((size_t)WT_TOT * 2);
    u16* xb    = (u16*)alloc((size_t)NN * 256 * 2);
    u16* hb0   = (u16*)alloc((size_t)NN * HC * 2);
    u16* hb1   = (u16*)alloc((size_t)NN * HC * 2);
    float* hfin = (float*)alloc((size_t)NN * HC * 4);

    // CSR by destination + W cast
    hipMemsetAsync(cnt, 0, zspan, stream);
    k_count<<<(EE + 255) / 256, 256, 0, stream>>>(ei, cnt);
    k_bsum<<<NB1, 256, 0, stream>>>(cnt, bsum);
    k_bscan<<<1, 256, 0, stream>>>(bsum, bex, offs);
    k_offs<<<NB1, 256, 0, stream>>>(cnt, bex, offs, cnt, csr);
    k_fill<<<(EE + 255) / 256, 256, 0, stream>>>(ei, cnt, csr);
    k_castw_all<<<(WT_TOT + 255) / 256, 256, 0, stream>>>(
        Wl[0], Wr[0], Wl[1], Wr[1], Wl[2], Wr[2], Wl[3], Wr[3], WtAll);

    const int GB = (NN + 127) / 128;   // 391
    const u16* Wt_l[4] = {WtAll, WtAll + WT_L0, WtAll + WT_L0 + WT_LX,
                          WtAll + WT_L0 + 2 * WT_LX};
    const u16* hb_in = nullptr;
    u16* hbb[2] = {hb0, hb1};
    for (int l = 0; l < 4; ++l) {
        if (l == 0) k_gemm<768, true ><<<GB, 512, 0, stream>>>((const void*)x, Wt_l[0], xb);
        else        k_gemm<128, false><<<GB, 512, 0, stream>>>((const void*)hb_in, Wt_l[l], xb);
        u16* ob = (l < 3) ? hbb[l & 1] : nullptr;
        float* of = (l == 3) ? hfin : nullptr;
        k_edge<<<(NN + 3) / 4, 256, 0, stream>>>(xb, att[l], bia[l], offs, csr, ob, of,
                                                 (l < 3) ? 1 : 0);
        hb_in = ob;
    }

    k_colsum<<<504, 256, 0, stream>>>(hfin, gsum);
    k_clf<<<1, 128, 0, stream>>>(gsum, clfW, clfb, outp);
}

// Round 7
// 388.795 us; speedup vs baseline: 2.7585x; 1.0147x over previous
//
#include <hip/hip_runtime.h>
#include <hip/hip_bf16.h>

#define NN 50000
#define EE 640000
#define HC 128
#define NB1 196   // ceil(NN/256)

typedef short bf16x8 __attribute__((ext_vector_type(8)));
typedef float f32x4 __attribute__((ext_vector_type(4)));
typedef unsigned short u16;

__device__ __forceinline__ u16 f2b(float f) {   // RN-even
    unsigned u = __float_as_uint(f);
    unsigned r = u + 0x7FFFu + ((u >> 16) & 1u);
    return (u16)(r >> 16);
}
__device__ __forceinline__ float b2f(u16 h) {
    return __uint_as_float(((unsigned)h) << 16);
}

__device__ __forceinline__ void gload_lds16(const void* g, void* l) {
    __builtin_amdgcn_global_load_lds((const __attribute__((address_space(1))) void*)g,
                                     (__attribute__((address_space(3))) void*)l, 16, 0, 0);
}

// sum across each 16-lane row, all lanes get result: pure DPP (no LDS op)
__device__ __forceinline__ float red16(float x) {
    x += __int_as_float(__builtin_amdgcn_update_dpp(0, __float_as_int(x), 0xB1, 0xF, 0xF, true));
    x += __int_as_float(__builtin_amdgcn_update_dpp(0, __float_as_int(x), 0x4E, 0xF, 0xF, true));
    x += __int_as_float(__builtin_amdgcn_update_dpp(0, __float_as_int(x), 0x141, 0xF, 0xF, true));
    x += __int_as_float(__builtin_amdgcn_update_dpp(0, __float_as_int(x), 0x128, 0xF, 0xF, true));
    return x;
}

// ---------------- CSR build ----------------

__global__ void k_count(const int* __restrict__ ei, int* __restrict__ cnt) {
    int e = blockIdx.x * blockDim.x + threadIdx.x;
    if (e < EE) atomicAdd(&cnt[ei[EE + e]], 1);
}

__global__ void k_bsum(const int* __restrict__ cnt, int* __restrict__ bsum) {
    __shared__ int sd[256];
    int b = blockIdx.x, t = threadIdx.x, i = b * 256 + t;
    sd[t] = (i < NN) ? cnt[i] + 1 : 0;
    __syncthreads();
    for (int o = 128; o; o >>= 1) { if (t < o) sd[t] += sd[t + o]; __syncthreads(); }
    if (!t) bsum[b] = sd[0];
}

// offs + block-scan-of-bsum + self-loop + cursor init, all fused (cursor aliases cnt)
__global__ void k_offs(const int* __restrict__ cnt_in, const int* __restrict__ bsum,
                       int* __restrict__ offs, int* __restrict__ cursor,
                       int* __restrict__ csr) {
    __shared__ int sb[256];
    __shared__ int sd[256];
    int b = blockIdx.x, t = threadIdx.x, i = b * 256 + t;
    sb[t] = (t < NB1) ? bsum[t] : 0;
    int v = (i < NN) ? cnt_in[i] + 1 : 0;
    sd[t] = v;
    __syncthreads();
    for (int o = 1; o < 256; o <<= 1) {
        int u1 = (t >= o) ? sd[t - o] : 0;
        int u2 = (t >= o) ? sb[t - o] : 0;
        __syncthreads();
        sd[t] += u1; sb[t] += u2;
        __syncthreads();
    }
    int bex = (b > 0) ? sb[b - 1] : 0;
    if (i < NN) {
        int o = bex + sd[t] - v;
        offs[i] = o;
        csr[o] = i;          // self loop first
        cursor[i] = o + 1;
    }
    if (b == NB1 - 1 && t == 0) offs[NN] = sb[NB1 - 1];
}

__global__ void k_fill(const int* __restrict__ ei, int* __restrict__ cursor,
                       int* __restrict__ csr) {
    int e = blockIdx.x * blockDim.x + threadIdx.x;
    if (e < EE) {
        int s = ei[e], d = ei[EE + e];
        int pos = atomicAdd(&cursor[d], 1);
        csr[pos] = s;
    }
}

// ---------------- all-layer W cast+transpose ----------------

#define WT_L0 196608              // 256*768
#define WT_LX 32768               // 256*128
#define WT_TOT (WT_L0 + 3 * WT_LX)

__global__ void k_castw_all(const float* __restrict__ Wl1, const float* __restrict__ Wr1,
                            const float* __restrict__ Wl2, const float* __restrict__ Wr2,
                            const float* __restrict__ Wl3, const float* __restrict__ Wr3,
                            const float* __restrict__ Wl4, const float* __restrict__ Wr4,
                            u16* __restrict__ WtAll) {
    int gid = blockIdx.x * 256 + threadIdx.x;
    if (gid >= WT_TOT) return;
    const float *Wl, *Wr;
    int idx, K, base;
    if (gid < WT_L0) { Wl = Wl1; Wr = Wr1; idx = gid; K = 768; base = 0; }
    else {
        int r = gid - WT_L0;
        int l = r >> 15; idx = r & (WT_LX - 1); K = 128; base = WT_L0 + l * WT_LX;
        if (l == 0)      { Wl = Wl2; Wr = Wr2; }
        else if (l == 1) { Wl = Wl3; Wr = Wr3; }
        else             { Wl = Wl4; Wr = Wr4; }
    }
    int c = idx / K, k = idx - c * K;
    float v = (c < 128) ? Wl[k * 128 + c] : Wr[k * 128 + (c - 128)];
    WtAll[base + idx] = f2b(v);
}

// ---------------- MFMA bf16 GEMM, 2-phase double-buffered (T3 minimum) ----------------
// xb[N][256] = A[N,K] @ Wt^T (bf16 out). Tile 64 rows x 256 cols, 4 waves (64x64 cols each),
// BK=32, 256 threads. LDS: As[2][64*32] (8KB), Bs[2][256*32] (32KB) = 40KB -> 4 blocks/CU.
// 16B-chunk XOR swizzle: phys_chunk = chunk ^ ((row>>1)&3)  (rows are 64B; gives 2-way = free).
// Schedule per k-step: issue stage(t+1 -> buf c^1) BEFORE MFMA(buf c); ONE barrier per step.

template<int K, bool F32A>
__global__ __launch_bounds__(256, 4)
void k_gemm(const void* __restrict__ Ag, const u16* __restrict__ Wt,
            u16* __restrict__ xb) {
    __shared__ __align__(16) u16 As[2][64 * 32];
    __shared__ __align__(16) u16 Bs[2][256 * 32];
    const int tid = threadIdx.x;
    const int wv = tid >> 6, ln = tid & 63;
    const int m0 = blockIdx.x * 64;
    const int lrow = ln & 15, g = ln >> 4;
    constexpr int NSTEP = K / 32;

    f32x4 acc[4][4] = {};

    const float* Af = (const float*)Ag;
    const u16* Ab = (const u16*)Ag;
    // A staging geometry (both paths): thread covers row tid>>2 (0..63), chunk tid&3
    const int arow = tid >> 2, aq = tid & 3;
    int arg = m0 + arow; if (arg >= NN) arg = 0;
    const int alc = aq ^ ((arow >> 1) & 3);       // swizzled source/dest chunk
    float4 rx, ry;

#define LOADREGS(ks) { const float* s_ = Af + (size_t)arg * K + (ks) * 32 + aq * 8; \
                       rx = *(const float4*)(s_); ry = *(const float4*)(s_ + 4); }
#define WRITEA(c) { bf16x8 v_; \
        v_[0] = (short)f2b(rx.x); v_[1] = (short)f2b(rx.y); \
        v_[2] = (short)f2b(rx.z); v_[3] = (short)f2b(rx.w); \
        v_[4] = (short)f2b(ry.x); v_[5] = (short)f2b(ry.y); \
        v_[6] = (short)f2b(ry.z); v_[7] = (short)f2b(ry.w); \
        *(bf16x8*)&As[c][arow * 32 + alc * 8] = v_; }
#define STAGEB(ks, c) { \
        _Pragma("unroll") \
        for (int q = 0; q < 4; ++q) { \
            int seg = (wv * 4 + q) * 64 + ln; \
            int row = seg >> 2, cc = seg & 3; \
            int lc = cc ^ ((row >> 1) & 3); \
            gload_lds16(Wt + (size_t)row * K + (ks) * 32 + lc * 8, &Bs[c][(wv * 4 + q) * 512]); \
        } }
#define STAGEAB(ks, c) gload_lds16(Ab + (size_t)arg * K + (ks) * 32 + alc * 8, &As[c][wv * 512]);

    // prologue
    if constexpr (F32A) {
        LOADREGS(0)
        WRITEA(0)
        STAGEB(0, 0)
        if (NSTEP > 1) LOADREGS(1)
    } else {
        STAGEAB(0, 0)
        STAGEB(0, 0)
    }
    __syncthreads();

    for (int t = 0; t < NSTEP; ++t) {
        const int c = t & 1;
        if (t + 1 < NSTEP) {
            STAGEB(t + 1, c ^ 1)
            if constexpr (F32A) {
                WRITEA(c ^ 1)                       // regs hold A(t+1)
                if (t + 2 < NSTEP) LOADREGS(t + 2)  // issue early, consume after next barrier
            } else {
                STAGEAB(t + 1, c ^ 1)
            }
        }
        // compute on buffer c
        bf16x8 af[4], bfr[4];
        #pragma unroll
        for (int f = 0; f < 4; ++f) {
            int r = f * 16 + lrow;
            af[f] = *(const bf16x8*)&As[c][r * 32 + ((g ^ ((r >> 1) & 3)) * 8)];
            int cr = wv * 64 + f * 16 + lrow;
            bfr[f] = *(const bf16x8*)&Bs[c][cr * 32 + ((g ^ ((cr >> 1) & 3)) * 8)];
        }
        #pragma unroll
        for (int i = 0; i < 4; ++i)
            #pragma unroll
            for (int j = 0; j < 4; ++j)
                acc[i][j] = __builtin_amdgcn_mfma_f32_16x16x32_bf16(af[i], bfr[j], acc[i][j], 0, 0, 0);
        if (t + 1 < NSTEP) __syncthreads();
    }
#undef LOADREGS
#undef WRITEA
#undef STAGEB
#undef STAGEAB

    const int crow0 = m0 + (g << 2);
    const int ccol0 = wv * 64 + lrow;
    #pragma unroll
    for (int i = 0; i < 4; ++i)
        #pragma unroll
        for (int rr = 0; rr < 4; ++rr) {
            int row = crow0 + i * 16 + rr;
            if (row < NN) {
                #pragma unroll
                for (int j = 0; j < 4; ++j)
                    xb[(size_t)row * 256 + ccol0 + j * 16] = f2b(acc[i][j][rr]);
            }
        }
}

// ---------------- per-node online-softmax GATv2 aggregation ----------------
// ONE WAVE per node; lane ln owns channel pair ch0 = (ln>>4)*32 + (ln&15)*2.
// Indices loaded 64-wide coalesced, broadcast via __shfl (readlane); 4 gather streams.
// Single-exp online update: d=e-m, t=exp(-|d|) -> {c,w} by select (saves 1 transcendental).

__global__ __launch_bounds__(256)
void k_edge(const u16* __restrict__ xb, const float* __restrict__ att,
            const float* __restrict__ bias, const int* __restrict__ offs,
            const int* __restrict__ csr, u16* __restrict__ outb,
            float* __restrict__ outf, int relu) {
    int i = blockIdx.x * 4 + (threadIdx.x >> 6);
    if (i >= NN) return;
    int ln = threadIdx.x & 63;
    int ch0 = ((ln >> 4) << 5) + ((ln & 15) << 1);

    unsigned xr2 = *(const unsigned*)&xb[(size_t)i * 256 + 128 + ch0];
    float xri0 = b2f((u16)xr2), xri1 = b2f((u16)(xr2 >> 16));
    float2 atv = *(const float2*)&att[ch0];
    const float at0 = atv.x, at1 = atv.y;
    int beg = offs[i];
    int deg = offs[i + 1] - beg;

    float m0v = -3.0e38f, s0v = 0.f, p00 = 0.f, p01 = 0.f;
    float m1v = -3.0e38f, s1v = 0.f, p10 = 0.f, p11 = 0.f;
    float m2v = -3.0e38f, s2v = 0.f, p20 = 0.f, p21 = 0.f;
    float m3v = -3.0e38f, s3v = 0.f, p30 = 0.f, p31 = 0.f;

#define GATH(k, jj) unsigned w##k = *(const unsigned*)&xb[(size_t)(jj) * 256 + ch0];
#define UPD(k, M, S, A0, A1) { \
    float v0 = b2f((u16)w##k), v1 = b2f((u16)(w##k >> 16)); \
    float u0 = v0 + xri0; u0 = fmaxf(u0, 0.2f * u0); \
    float u1 = v1 + xri1; u1 = fmaxf(u1, 0.2f * u1); \
    float e = red16(u0 * at0 + u1 * at1); \
    float d = e - M; \
    float tt = __expf(-fabsf(d)); \
    bool ng = (d <= 0.f); \
    float c = ng ? 1.f : tt; \
    float ww = ng ? tt : 1.f; \
    M = ng ? M : e; \
    S = S * c + ww; A0 = A0 * c + ww * v0; A1 = A1 * c + ww * v1; }

    for (int base = 0; base < deg; base += 64) {
        int lim = deg - base; if (lim > 64) lim = 64;
        int idxv = (base + ln < deg) ? csr[beg + base + ln] : 0;
        int p = 0;
        for (; p + 4 <= lim; p += 4) {
            int j0 = __shfl(idxv, p);
            int j1 = __shfl(idxv, p + 1);
            int j2 = __shfl(idxv, p + 2);
            int j3 = __shfl(idxv, p + 3);
            GATH(0, j0) GATH(1, j1) GATH(2, j2) GATH(3, j3)
            UPD(0, m0v, s0v, p00, p01)
            UPD(1, m1v, s1v, p10, p11)
            UPD(2, m2v, s2v, p20, p21)
            UPD(3, m3v, s3v, p30, p31)
        }
        for (; p < lim; ++p) {
            int j0 = __shfl(idxv, p);
            GATH(4, j0)
            UPD(4, m0v, s0v, p00, p01)
        }
    }
#undef GATH
#undef UPD

    float mm = fmaxf(fmaxf(m0v, m1v), fmaxf(m2v, m3v));
    float c0 = __expf(m0v - mm), c1 = __expf(m1v - mm);
    float c2 = __expf(m2v - mm), c3 = __expf(m3v - mm);
    float s = s0v * c0 + s1v * c1 + s2v * c2 + s3v * c3 + 1e-16f;
    float inv = 1.f / s;
    float2 bv = *(const float2*)&bias[ch0];
    float o0 = (p00 * c0 + p10 * c1 + p20 * c2 + p30 * c3) * inv + bv.x;
    float o1 = (p01 * c0 + p11 * c1 + p21 * c2 + p31 * c3) * inv + bv.y;
    if (relu) { o0 = fmaxf(o0, 0.f); o1 = fmaxf(o1, 0.f); }
    if (outb) {
        unsigned pk = (unsigned)f2b(o0) | ((unsigned)f2b(o1) << 16);
        *(unsigned*)&outb[(size_t)i * HC + ch0] = pk;
    }
    if (outf) {
        *(float2*)&outf[(size_t)i * HC + ch0] = make_float2(o0, o1);
    }
}

// ---------------- tail ----------------

__global__ __launch_bounds__(256)
void k_colsum(const float* __restrict__ h, float* __restrict__ gsum) {
    __shared__ float4 sd[8][32];
    int t = threadIdx.x;
    int c4 = t & 31, rl = t >> 5;
    float sx = 0.f, sy = 0.f, sz = 0.f, sw = 0.f;
    for (int r = blockIdx.x * 8 + rl; r < NN; r += 8 * gridDim.x) {
        float4 v = *(const float4*)&h[(size_t)r * HC + c4 * 4];
        sx += v.x; sy += v.y; sz += v.z; sw += v.w;
    }
    sd[rl][c4] = make_float4(sx, sy, sz, sw);
    __syncthreads();
    if (rl == 0) {
        float4 a = sd[0][c4];
        #pragma unroll
        for (int q = 1; q < 8; ++q) {
            float4 b = sd[q][c4];
            a.x += b.x; a.y += b.y; a.z += b.z; a.w += b.w;
        }
        atomicAdd(&gsum[c4 * 4 + 0], a.x);
        atomicAdd(&gsum[c4 * 4 + 1], a.y);
        atomicAdd(&gsum[c4 * 4 + 2], a.z);
        atomicAdd(&gsum[c4 * 4 + 3], a.w);
    }
}

__global__ void k_clf(const float* __restrict__ gsum, const float* __restrict__ W,
                      const float* __restrict__ bcls, float* __restrict__ out) {
    __shared__ float v[HC];
    int t = threadIdx.x;   // 128
    v[t] = gsum[t] * (1.f / (float)NN);
    __syncthreads();
    if (t < 2) {
        float r = 0.f;
        for (int k = 0; k < HC; ++k) r += v[k] * W[k * 2 + t];
        out[t] = r + bcls[t];
    }
}

// ---------------- launch ----------------

extern "C" void kernel_launch(void* const* d_in, const int* in_sizes, int n_in,
                              void* d_out, int out_size, void* d_ws, size_t ws_size,
                              hipStream_t stream) {
    const float* x = (const float*)d_in[0];
    const int* ei = (const int*)d_in[1];
    const float *Wl[4], *Wr[4], *att[4], *bia[4];
    for (int l = 0; l < 4; ++l) {
        Wl[l] = (const float*)d_in[2 + 4 * l];
        Wr[l] = (const float*)d_in[3 + 4 * l];
        att[l] = (const float*)d_in[4 + 4 * l];
        bia[l] = (const float*)d_in[5 + 4 * l];
    }
    const float* clfW = (const float*)d_in[18];
    const float* clfb = (const float*)d_in[19];
    float* outp = (float*)d_out;

    char* w = (char*)d_ws;
    size_t o = 0;
    auto alloc = [&](size_t bytes) {
        char* p = w + o;
        o = (o + bytes + 255) & ~(size_t)255;
        return p;
    };
    int* cnt    = (int*)alloc((size_t)NN * 4);     // also cursor
    float* gsum = (float*)alloc(HC * 4);           // adjacent to cnt: one memset covers both
    size_t zspan = o;                              // bytes from cnt to end of gsum (padded)
    int* offs  = (int*)alloc((size_t)(NN + 1) * 4);
    int* csr   = (int*)alloc((size_t)(EE + NN) * 4);
    int* bsum  = (int*)alloc((size_t)NB1 * 4);
    u16* WtAll = (u16*)alloc((size_t)WT_TOT * 2);
    u16* xb    = (u16*)alloc((size_t)NN * 256 * 2);
    u16* hb0   = (u16*)alloc((size_t)NN * HC * 2);
    u16* hb1   = (u16*)alloc((size_t)NN * HC * 2);
    float* hfin = (float*)alloc((size_t)NN * HC * 4);

    // CSR by destination + W cast
    hipMemsetAsync(cnt, 0, zspan, stream);
    k_count<<<(EE + 255) / 256, 256, 0, stream>>>(ei, cnt);
    k_bsum<<<NB1, 256, 0, stream>>>(cnt, bsum);
    k_offs<<<NB1, 256, 0, stream>>>(cnt, bsum, offs, cnt, csr);
    k_fill<<<(EE + 255) / 256, 256, 0, stream>>>(ei, cnt, csr);
    k_castw_all<<<(WT_TOT + 255) / 256, 256, 0, stream>>>(
        Wl[0], Wr[0], Wl[1], Wr[1], Wl[2], Wr[2], Wl[3], Wr[3], WtAll);

    const int GB = (NN + 63) / 64;   // 782
    const u16* Wt_l[4] = {WtAll, WtAll + WT_L0, WtAll + WT_L0 + WT_LX,
                          WtAll + WT_L0 + 2 * WT_LX};
    const u16* hb_in = nullptr;
    u16* hbb[2] = {hb0, hb1};
    for (int l = 0; l < 4; ++l) {
        if (l == 0) k_gemm<768, true ><<<GB, 256, 0, stream>>>((const void*)x, Wt_l[0], xb);
        else        k_gemm<128, false><<<GB, 256, 0, stream>>>((const void*)hb_in, Wt_l[l], xb);
        u16* ob = (l < 3) ? hbb[l & 1] : nullptr;
        float* of = (l == 3) ? hfin : nullptr;
        k_edge<<<(NN + 3) / 4, 256, 0, stream>>>(xb, att[l], bia[l], offs, csr, ob, of,
                                                 (l < 3) ? 1 : 0);
        hb_in = ob;
    }

    k_colsum<<<504, 256, 0, stream>>>(hfin, gsum);
    k_clf<<<1, 128, 0, stream>>>(gsum, clfW, clfb, outp);
}